// Round 6
// baseline (167.820 us; speedup 1.0000x reference)
//
#include <hip/hip_runtime.h>
#include <math.h>

#define THREADS 256
#define BM 128
#define QBK 64                    // fp8 K per iteration (64 B row slice)
#define EPSV 1e-5f
#define C1E 11.023176380641601f   // e^2.4
#define C2E 9.025013499434122f    // e^2.2
#define FP8_SCALE 256.0f          // power-of-2 row scale into e4m3 range
#define INV_SCALE2 1.52587890625e-5f   // 1/65536, exact

typedef float f32x4 __attribute__((ext_vector_type(4)));

// ---------------------------------------------------------------------------
// Kernel A (fp8 path): normalize row, scale by 256, convert to OCP e4m3.
// Also zero-inits d_out (block 0) so the separate memset launch is dropped.
// ---------------------------------------------------------------------------
__launch_bounds__(THREADS)
__global__ void norm_conv_fp8_kernel(const float* __restrict__ x,
                                     unsigned char* __restrict__ xq,
                                     float* __restrict__ out, int D) {
    const int row = blockIdx.x;
    const float4* x4 = (const float4*)(x + (size_t)row * D);
    const int tid = threadIdx.x;
    if (row == 0 && tid == 0) out[0] = 0.f;

    float s = 0.f;
    for (int b = tid * 2; b * 4 < D; b += THREADS * 2) {
        float4 v0 = x4[b];
        float4 v1 = x4[b + 1];
        s += v0.x * v0.x + v0.y * v0.y + v0.z * v0.z + v0.w * v0.w
           + v1.x * v1.x + v1.y * v1.y + v1.z * v1.z + v1.w * v1.w;
    }
#pragma unroll
    for (int off = 32; off > 0; off >>= 1) s += __shfl_down(s, off, 64);
    __shared__ float red[THREADS / 64 + 1];
    if ((tid & 63) == 0) red[tid >> 6] = s;
    __syncthreads();
    if (tid == 0) {
        float tot = 0.f;
#pragma unroll
        for (int w = 0; w < THREADS / 64; ++w) tot += red[w];
        red[THREADS / 64] = FP8_SCALE / fmaxf(sqrtf(tot), 1e-12f);
    }
    __syncthreads();
    const float sc = red[THREADS / 64];

    int2* outq = (int2*)(xq + (size_t)row * D);
    for (int b = tid * 2; b * 4 < D; b += THREADS * 2) {
        float4 v0 = x4[b];
        float4 v1 = x4[b + 1];
        int lo = __builtin_amdgcn_cvt_pk_fp8_f32(v0.x * sc, v0.y * sc, 0, 0);
        lo = __builtin_amdgcn_cvt_pk_fp8_f32(v0.z * sc, v0.w * sc, lo, 1);
        int hi = __builtin_amdgcn_cvt_pk_fp8_f32(v1.x * sc, v1.y * sc, 0, 0);
        hi = __builtin_amdgcn_cvt_pk_fp8_f32(v1.z * sc, v1.w * sc, hi, 1);
        int2 o; o.x = lo; o.y = hi;
        outq[b >> 1] = o;
    }
}

// Plain inv-norm (fallback path).
__global__ void row_inv_norm_kernel(const float* __restrict__ x,
                                    float* __restrict__ inv_norm, int D) {
    const int row = blockIdx.x;
    const float4* x4 = (const float4*)(x + (size_t)row * D);
    const int nf4 = D >> 2;
    float s = 0.f;
    for (int i = threadIdx.x; i < nf4; i += THREADS) {
        float4 v = x4[i];
        s += v.x * v.x + v.y * v.y + v.z * v.z + v.w * v.w;
    }
#pragma unroll
    for (int off = 32; off > 0; off >>= 1) s += __shfl_down(s, off, 64);
    __shared__ float red[THREADS / 64];
    if ((threadIdx.x & 63) == 0) red[threadIdx.x >> 6] = s;
    __syncthreads();
    if (threadIdx.x == 0) {
        float tot = 0.f;
#pragma unroll
        for (int w = 0; w < THREADS / 64; ++w) tot += red[w];
        inv_norm[row] = 1.0f / fmaxf(sqrtf(tot), 1e-12f);
    }
}

#define GLDS16(g, l)                                                          \
    __builtin_amdgcn_global_load_lds(                                         \
        (const __attribute__((address_space(1))) unsigned int*)(g),           \
        (__attribute__((address_space(3))) unsigned int*)(l), 16, 0, 0)

// ---------------------------------------------------------------------------
// Kernel B: SYMMETRIC fp8 Gram. R6:
//   - __launch_bounds__(256, 3) + FUSED epilogue. Ledger across rounds:
//     3 blocks/CU + spill (R3/R5: 86 us) < 2 blocks/CU clean (R4: 94 us);
//     target = 3 blocks/CU AND clean. The 2-pass epilogue keeps all 64
//     accv values live across both passes (dd write-back) -> needs ~110
//     arch regs -> spills ~36 f32 at the 84-arch budget (R5 WRITE_SIZE
//     40.6 MB vs 4.2 MB real). FUSION (R2-proven math, absmax 0.0):
//     column partials accumulate in ca[4][8] during the row pass, accv
//     dies at its single read -> streaming acc->arch, est. ~75 arch.
//     SUCCESS CRITERION: WRITE_SIZE == 4224 KB.
//   - Triple-buffered staging (3 x 16 KB LDS) with counted vmcnt (R3-R5):
//     per iter: s_waitcnt vmcnt(4) -> s_barrier -> stage tile t+2 ->
//     ds_read + 32 MFMA. ~2 iterations of lead per load; no mid-loop drain.
// Staging swizzle (QBK=64): LDS slot q of row r holds global chunk
// q ^ ((r>>1)&3); fragment read of k-slot sl=ks*4+quad lives at byte
// r*64 + (((sl>>1)^((r>>1)&3))<<4) + ((sl&1)<<3); ks=1 is ks=0 ^ 32.
// vals: 0 s_pos_intra 1 cnt_pi 2 s_pos_cross 3 cnt_pc
//       4 DE_neg_intra 5 E_neg_intra 6 DE_neg_cross 7 E_neg_cross
// ---------------------------------------------------------------------------
__launch_bounds__(THREADS, 3)
__global__ void gram_fp8_kernel(const unsigned char* __restrict__ xq,
                                const int* __restrict__ targets,
                                const int* __restrict__ sub,
                                float* __restrict__ pr,
                                float* __restrict__ pc,
                                int D) {
    __shared__ unsigned char As[3][BM * QBK];   // 3 x 8 KB
    __shared__ unsigned char Bs[3][BM * QBK];   // 3 x 8 KB

    // XCD-chunked tile mapping (bijective: gridDim.x % 8 == 0).
    int tk = blockIdx.x;
    if ((gridDim.x & 7) == 0) {
        const int per = gridDim.x >> 3;
        tk = (tk & 7) * per + (tk >> 3);
    }

    // Triangular decode: tk = bx*(bx+1)/2 + by, by <= bx.
    int bx = (int)((sqrtf(8.0f * tk + 1.0f) - 1.0f) * 0.5f);
    while ((bx + 1) * (bx + 2) / 2 <= tk) ++bx;
    while (bx * (bx + 1) / 2 > tk) --bx;
    const int by = tk - bx * (bx + 1) / 2;

    const int tid = threadIdx.x;
    const int w = tid >> 6;          // wave 0..3
    const int lane = tid & 63;
    const int wm = w >> 1;           // row half (0..1)
    const int wn = w & 1;            // col half (0..1)
    const int quad = lane >> 4;
    const int cl = lane & 15;

    const int rowA0 = by * BM;
    const int colB0 = bx * BM;

    // Staging: per matrix 512 chunks of 16B (128 rows x 4); thread covers
    // chunks c = l*256 + tid, l=0..1. r = c>>2 = l*64 + (tid>>2);
    // source slot qs = (tid&3) ^ ((r>>1)&3) = (tid&3) ^ ((tid>>3)&3).
    const int qs = (tid & 3) ^ ((tid >> 3) & 3);
    const unsigned char* sA[2];
    const unsigned char* sB[2];
    int dof[2];
#pragma unroll
    for (int l = 0; l < 2; ++l) {
        const int r = l * 64 + (tid >> 2);
        sA[l] = xq + (size_t)(rowA0 + r) * D + qs * 16;
        sB[l] = xq + (size_t)(colB0 + r) * D + qs * 16;
        dof[l] = (l * 256 + w * 64) * 16;   // wave-uniform byte base
    }

    // Fragment byte offsets for ks=0; ks=1 = ^32 (chunk bit1 flips).
    int aoff[4], boff[4];
#pragma unroll
    for (int mi = 0; mi < 4; ++mi) {
        const int ar = wm * 64 + mi * 16 + cl;
        aoff[mi] = ar * QBK + (((quad >> 1) ^ ((ar >> 1) & 3)) << 4)
                 + ((quad & 1) << 3);
    }
#pragma unroll
    for (int ni = 0; ni < 4; ++ni) {
        const int br = wn * 64 + ni * 16 + cl;
        boff[ni] = br * QBK + (((quad >> 1) ^ ((br >> 1) & 3)) << 4)
                 + ((quad & 1) << 3);
    }

    f32x4 accv[4][4];
#pragma unroll
    for (int mi = 0; mi < 4; ++mi)
#pragma unroll
        for (int ni = 0; ni < 4; ++ni) accv[mi][ni] = (f32x4)(0.f);

    const int nIter = D / QBK;

    // Prologue: stage tiles 0,1 into bufs 0,1 (8 vmem/wave outstanding).
#pragma unroll
    for (int l = 0; l < 2; ++l) {
        GLDS16(sA[l], &As[0][0] + dof[l]);
        GLDS16(sB[l], &Bs[0][0] + dof[l]);
    }
#pragma unroll
    for (int l = 0; l < 2; ++l) {
        GLDS16(sA[l] + QBK, &As[1][0] + dof[l]);
        GLDS16(sB[l] + QBK, &Bs[1][0] + dof[l]);
    }

    int cs = 0;          // t % 3
    int ps = 2;          // (t+2) % 3
    for (int t = 0; t < nIter; ++t) {
        // Tile t's 4 loads done; tile t+1's 4 may remain in flight.
        if (t + 1 < nIter)
            asm volatile("s_waitcnt vmcnt(4)" ::: "memory");
        else
            asm volatile("s_waitcnt vmcnt(0)" ::: "memory");
        __builtin_amdgcn_s_barrier();

        if (t + 2 < nIter) {
            const int kb = (t + 2) * QBK;
#pragma unroll
            for (int l = 0; l < 2; ++l) {
                GLDS16(sA[l] + kb, &As[ps][0] + dof[l]);
                GLDS16(sB[l] + kb, &Bs[ps][0] + dof[l]);
            }
        }

        const unsigned char* Ac = &As[cs][0];
        const unsigned char* Bc = &Bs[cs][0];
        long af[4], bf[4];
#pragma unroll
        for (int mi = 0; mi < 4; ++mi)
            af[mi] = *(const long*)(Ac + aoff[mi]);
#pragma unroll
        for (int ni = 0; ni < 4; ++ni)
            bf[ni] = *(const long*)(Bc + boff[ni]);
#pragma unroll
        for (int mi = 0; mi < 4; ++mi)
#pragma unroll
            for (int ni = 0; ni < 4; ++ni)
                accv[mi][ni] = __builtin_amdgcn_mfma_f32_16x16x32_fp8_fp8(
                    af[mi], bf[ni], accv[mi][ni], 0, 0, 0);
#pragma unroll
        for (int mi = 0; mi < 4; ++mi)
            af[mi] = *(const long*)(Ac + (aoff[mi] ^ 32));
#pragma unroll
        for (int ni = 0; ni < 4; ++ni)
            bf[ni] = *(const long*)(Bc + (boff[ni] ^ 32));
#pragma unroll
        for (int mi = 0; mi < 4; ++mi)
#pragma unroll
            for (int ni = 0; ni < 4; ++ni)
                accv[mi][ni] = __builtin_amdgcn_mfma_f32_16x16x32_fp8_fp8(
                    af[mi], bf[ni], accv[mi][ni], 0, 0, 0);

        cs = (cs == 2) ? 0 : cs + 1;
        ps = (ps == 2) ? 0 : ps + 1;
    }

    // ------------- FUSED epilogue: row partials + col partials -------------
    // C/D map: col = cl, row = quad*4 + reg. Dots carry scale 65536.
    // Column stats accumulate in ca[ni][8] (statically indexed) during the
    // row pass; accv elements die at their single read (no dd write-back).
    int tj[4], sj[4];
#pragma unroll
    for (int ni = 0; ni < 4; ++ni) {
        const int gc = colB0 + wn * 64 + ni * 16 + cl;
        tj[ni] = targets[gc];
        sj[ni] = sub[gc];
    }

    float ca[4][8];
#pragma unroll
    for (int ni = 0; ni < 4; ++ni)
#pragma unroll
        for (int k = 0; k < 8; ++k) ca[ni][k] = 0.f;

    float* rowp = (float*)&As[0][0];   // reuse buf0: [2][128][8] = 8 KB
#pragma unroll
    for (int mi = 0; mi < 4; ++mi) {
#pragma unroll
        for (int r = 0; r < 4; ++r) {
            const int rloc = wm * 64 + mi * 16 + quad * 4 + r;
            const int gi = rowA0 + rloc;
            const int ti = targets[gi];     // L1-hot broadcast
            const int si = sub[gi];

            float s0 = 0.f, s1 = 0.f, s2 = 0.f, s3 = 0.f;
            float s4 = 0.f, s5 = 0.f, s6 = 0.f, s7 = 0.f;
#pragma unroll
            for (int ni = 0; ni < 4; ++ni) {
                const int gj = colB0 + wn * 64 + ni * 16 + cl;
                const float d2 =
                    fmaf(-2.0f * INV_SCALE2, accv[mi][ni][r], 2.0f);
                const float dd = sqrtf(fmaxf(d2, 1e-12f));
                const bool same = (ti == tj[ni]);
                const bool intra = (si == sj[ni]);
                const bool pos = same && (gi != gj);
                const bool neg = !same;
                const float mg = intra ? 1.4f : 0.7f;
                const float v = fmaxf(dd - mg, 0.f);
                const float e = __expf(-dd);   // e^alpha folded in finalize
                const float de = dd * e;
                if (pos && intra)  { s0 += v;  s1 += 1.f;
                                     ca[ni][0] += v;  ca[ni][1] += 1.f; }
                if (pos && !intra) { s2 += v;  s3 += 1.f;
                                     ca[ni][2] += v;  ca[ni][3] += 1.f; }
                if (neg && intra)  { s4 += de; s5 += e;
                                     ca[ni][4] += de; ca[ni][5] += e; }
                if (neg && !intra) { s6 += de; s7 += e;
                                     ca[ni][6] += de; ca[ni][7] += e; }
            }
#pragma unroll
            for (int off = 1; off < 16; off <<= 1) {
                s0 += __shfl_xor(s0, off, 64);
                s1 += __shfl_xor(s1, off, 64);
                s2 += __shfl_xor(s2, off, 64);
                s3 += __shfl_xor(s3, off, 64);
                s4 += __shfl_xor(s4, off, 64);
                s5 += __shfl_xor(s5, off, 64);
                s6 += __shfl_xor(s6, off, 64);
                s7 += __shfl_xor(s7, off, 64);
            }
            if (cl == 0) {
                float* dst = rowp + ((wn << 7) + rloc) * 8;
                float4 p0 = {s0, s1, s2, s3};
                float4 p1 = {s4, s5, s6, s7};
                *(float4*)(dst) = p0;
                *(float4*)(dst + 4) = p1;
            }
        }
    }
    __syncthreads();
    {
        const size_t prbase = (size_t)tk * 1024;
        for (int i = tid; i < 1024; i += THREADS)
            pr[prbase + i] = rowp[i] + rowp[1024 + i];
    }

    // Column reduction: lane holds ca[ni][*] for its col over the quad's 16
    // rows of the wm half; reduce across quads (lanes +16,+32).
    float* colp = (float*)&Bs[0][0];   // reuse buf0: [2][128][8] = 8 KB
#pragma unroll
    for (int ni = 0; ni < 4; ++ni) {
        float t0 = ca[ni][0], t1 = ca[ni][1], t2 = ca[ni][2], t3 = ca[ni][3];
        float t4 = ca[ni][4], t5 = ca[ni][5], t6 = ca[ni][6], t7 = ca[ni][7];
        t0 += __shfl_xor(t0, 16, 64); t0 += __shfl_xor(t0, 32, 64);
        t1 += __shfl_xor(t1, 16, 64); t1 += __shfl_xor(t1, 32, 64);
        t2 += __shfl_xor(t2, 16, 64); t2 += __shfl_xor(t2, 32, 64);
        t3 += __shfl_xor(t3, 16, 64); t3 += __shfl_xor(t3, 32, 64);
        t4 += __shfl_xor(t4, 16, 64); t4 += __shfl_xor(t4, 32, 64);
        t5 += __shfl_xor(t5, 16, 64); t5 += __shfl_xor(t5, 32, 64);
        t6 += __shfl_xor(t6, 16, 64); t6 += __shfl_xor(t6, 32, 64);
        t7 += __shfl_xor(t7, 16, 64); t7 += __shfl_xor(t7, 32, 64);
        if (lane < 16) {
            const int colloc = wn * 64 + ni * 16 + lane;
            float* dst = colp + ((wm << 7) + colloc) * 8;
            float4 p0 = {t0, t1, t2, t3};
            float4 p1 = {t4, t5, t6, t7};
            *(float4*)(dst) = p0;
            *(float4*)(dst + 4) = p1;
        }
    }
    __syncthreads();
    {
        const float om = (bx == by) ? 0.f : 1.f;   // diag: zero col side
        const size_t pcbase = (size_t)tk * 1024;
        for (int i = tid; i < 1024; i += THREADS)
            pc[pcbase + i] = (colp[i] + colp[1024 + i]) * om;
    }
}

// ---------------------------------------------------------------------------
// Kernel C: gather 33 slices per row (nbx-B from pr, B+1 from pc; the
// diagonal pc slice is pre-zeroed), combine ratios, global mean.
// ---------------------------------------------------------------------------
__global__ void finalize_sym_kernel(const float* __restrict__ pr,
                                    const float* __restrict__ pc,
                                    float* __restrict__ out, int N, int nbx) {
    const int tid = threadIdx.x;
    const int rloc16 = tid >> 4;
    const int st = tid & 15;
    const int i = blockIdx.x * 16 + rloc16;
    const int B = i >> 7;
    const int rl = i & 127;
    const int nrow = nbx - B;          // pr-slice count
    const int ntot = nbx + 1;          // total slices (one is zero)

    float a0 = 0.f, a1 = 0.f, a2 = 0.f, a3 = 0.f;
    float a4 = 0.f, a5 = 0.f, a6 = 0.f, a7 = 0.f;
    for (int s = st; s < ntot; s += 16) {
        const float* base;
        if (s < nrow) {
            const int bxx = B + s;
            base = pr + ((size_t)(bxx * (bxx + 1) / 2 + B) * 128 + rl) * 8;
        } else {
            const int byy = s - nrow;
            base = pc + ((size_t)(B * (B + 1) / 2 + byy) * 128 + rl) * 8;
        }
        float4 u0 = *(const float4*)(base);
        float4 u1 = *(const float4*)(base + 4);
        a0 += u0.x; a1 += u0.y; a2 += u0.z; a3 += u0.w;
        a4 += u1.x; a5 += u1.y; a6 += u1.z; a7 += u1.w;
    }
#pragma unroll
    for (int off = 1; off < 16; off <<= 1) {
        a0 += __shfl_xor(a0, off, 64);
        a1 += __shfl_xor(a1, off, 64);
        a2 += __shfl_xor(a2, off, 64);
        a3 += __shfl_xor(a3, off, 64);
        a4 += __shfl_xor(a4, off, 64);
        a5 += __shfl_xor(a5, off, 64);
        a6 += __shfl_xor(a6, off, 64);
        a7 += __shfl_xor(a7, off, 64);
    }
    __shared__ float lred[16];
    if (st == 0) {
        const float l = a0 / (a1 + EPSV) + a2 / (a3 + EPSV)
            + (C1E * fmaf(2.4f, a5, -a4)) / (C1E * a5 + EPSV)
            + (C2E * fmaf(2.2f, a7, -a6)) / (C2E * a7 + EPSV);
        lred[rloc16] = l;
    }
    __syncthreads();
    if (tid == 0) {
        float tot = 0.f;
#pragma unroll
        for (int k2 = 0; k2 < 16; ++k2) tot += lred[k2];
        atomicAdd(out, tot / (float)N);
    }
}

// ---------------------------------------------------------------------------
// Fallback path (144 KB ws): fp32 tile GEMM + atomic epilogue (R1, known-good)
// ---------------------------------------------------------------------------
__launch_bounds__(THREADS, 2)
__global__ void dist_loss_kernel(const float* __restrict__ x,
                                 const int* __restrict__ targets,
                                 const int* __restrict__ sub,
                                 const float* __restrict__ inv_norm,
                                 float* __restrict__ acc,
                                 int N, int D) {
    __shared__ float Asf[16][128];
    __shared__ float Bsf[16][128];

    const int nbx = N / 128;
    const int bx = blockIdx.x % nbx;
    const int by = blockIdx.x / nbx;
    const int tid = threadIdx.x;
    const int tx = tid & 15;
    const int ty = tid >> 4;
    const int rowA0 = by * 128;
    const int colB0 = bx * 128;
    const float* Abase = x + (size_t)rowA0 * D;
    const float* Bbase = x + (size_t)colB0 * D;

    float accv[8][8];
#pragma unroll
    for (int r = 0; r < 8; ++r)
#pragma unroll
        for (int c = 0; c < 8; ++c) accv[r][c] = 0.f;

    for (int kb = 0; kb < D; kb += 16) {
#pragma unroll
        for (int l = 0; l < 2; ++l) {
            const int f = tid + l * THREADS;
            const int row = f >> 2;
            const int kq = (f & 3) << 2;
            float4 va = *(const float4*)(Abase + (size_t)row * D + kb + kq);
            float4 vb = *(const float4*)(Bbase + (size_t)row * D + kb + kq);
            Asf[kq + 0][row] = va.x; Asf[kq + 1][row] = va.y;
            Asf[kq + 2][row] = va.z; Asf[kq + 3][row] = va.w;
            Bsf[kq + 0][row] = vb.x; Bsf[kq + 1][row] = vb.y;
            Bsf[kq + 2][row] = vb.z; Bsf[kq + 3][row] = vb.w;
        }
        __syncthreads();
#pragma unroll
        for (int k = 0; k < 16; ++k) {
            float4 a0 = *(const float4*)&Asf[k][ty * 8];
            float4 a1 = *(const float4*)&Asf[k][ty * 8 + 4];
            float4 b0 = *(const float4*)&Bsf[k][tx * 8];
            float4 b1 = *(const float4*)&Bsf[k][tx * 8 + 4];
            float ar[8] = {a0.x, a0.y, a0.z, a0.w, a1.x, a1.y, a1.z, a1.w};
            float br[8] = {b0.x, b0.y, b0.z, b0.w, b1.x, b1.y, b1.z, b1.w};
#pragma unroll
            for (int r = 0; r < 8; ++r)
#pragma unroll
                for (int c = 0; c < 8; ++c)
                    accv[r][c] = fmaf(ar[r], br[c], accv[r][c]);
        }
        __syncthreads();
    }

    const int row_base = rowA0 + ty * 8;
    const int col_base = colB0 + tx * 8;
    int tjc[8], sjc[8];
    float invj[8];
#pragma unroll
    for (int c = 0; c < 8; ++c) {
        tjc[c] = targets[col_base + c];
        sjc[c] = sub[col_base + c];
        invj[c] = inv_norm[col_base + c];
    }
#pragma unroll
    for (int r = 0; r < 8; ++r) {
        const int gi = row_base + r;
        const int ti = targets[gi];
        const int si = sub[gi];
        const float invi = inv_norm[gi];
        float s0 = 0.f, s1 = 0.f, s2 = 0.f, s3 = 0.f;
        float s4 = 0.f, s5 = 0.f, s6 = 0.f, s7 = 0.f;
#pragma unroll
        for (int c = 0; c < 8; ++c) {
            const int gj = col_base + c;
            const float dot = accv[r][c] * invi * invj[c];
            const float dd = sqrtf(fmaxf(2.f - 2.f * dot, 1e-12f));
            const bool same = (ti == tjc[c]);
            const bool intra = (si == sjc[c]);
            const bool pos = same && (gi != gj);
            const bool neg = !same;
            const float df = (intra ? 2.4f : 2.2f) - dd;
            const float wgt = __expf(df);
            const float v = fmaxf(dd - (intra ? 1.4f : 0.7f), 0.f);
            if (pos && intra)  { s0 += v; s1 += 1.f; }
            if (pos && !intra) { s2 += v; s3 += 1.f; }
            if (neg && intra)  { s4 += df * wgt; s5 += wgt; }
            if (neg && !intra) { s6 += df * wgt; s7 += wgt; }
        }
#pragma unroll
        for (int off = 1; off < 16; off <<= 1) {
            s0 += __shfl_xor(s0, off, 64);
            s1 += __shfl_xor(s1, off, 64);
            s2 += __shfl_xor(s2, off, 64);
            s3 += __shfl_xor(s3, off, 64);
            s4 += __shfl_xor(s4, off, 64);
            s5 += __shfl_xor(s5, off, 64);
            s6 += __shfl_xor(s6, off, 64);
            s7 += __shfl_xor(s7, off, 64);
        }
        if (tx == 0) {
            float* a = acc + (size_t)gi * 8;
            atomicAdd(a + 0, s0); atomicAdd(a + 1, s1);
            atomicAdd(a + 2, s2); atomicAdd(a + 3, s3);
            atomicAdd(a + 4, s4); atomicAdd(a + 5, s5);
            atomicAdd(a + 6, s6); atomicAdd(a + 7, s7);
        }
    }
}

__global__ void finalize_kernel(const float* __restrict__ acc,
                                float* __restrict__ out, int N) {
    float s = 0.f;
    for (int i = threadIdx.x; i < N; i += THREADS) {
        const float* a = acc + (size_t)i * 8;
        s += a[0] / (a[1] + EPSV) + a[2] / (a[3] + EPSV)
           + a[4] / (a[5] + EPSV) + a[6] / (a[7] + EPSV);
    }
#pragma unroll
    for (int off = 32; off > 0; off >>= 1) s += __shfl_down(s, off, 64);
    __shared__ float red[THREADS / 64];
    if ((threadIdx.x & 63) == 0) red[threadIdx.x >> 6] = s;
    __syncthreads();
    if (threadIdx.x == 0) {
        float tot = 0.f;
#pragma unroll
        for (int w = 0; w < THREADS / 64; ++w) tot += red[w];
        out[0] = tot / (float)N;
    }
}

// ---------------------------------------------------------------------------
extern "C" void kernel_launch(void* const* d_in, const int* in_sizes, int n_in,
                              void* d_out, int out_size, void* d_ws, size_t ws_size,
                              hipStream_t stream) {
    const float* x = (const float*)d_in[0];
    const int* targets = (const int*)d_in[1];
    const int* sub = (const int*)d_in[2];
    const int N = in_sizes[1];
    const int D = in_sizes[0] / N;

    const int nbx = N / BM;
    const int T = nbx * (nbx + 1) / 2;
    const size_t sliceB = (size_t)T * 128 * 8 * sizeof(float);
    const size_t need = (size_t)N * D + 2 * sliceB;   // fp8: N*D bytes

    if (ws_size >= need) {
        unsigned char* xq = (unsigned char*)d_ws;     // N*D fp8
        float* pr = (float*)((char*)d_ws + (size_t)N * D);
        float* pc = pr + (size_t)T * 128 * 8;

        norm_conv_fp8_kernel<<<N, THREADS, 0, stream>>>(x, xq,
                                                        (float*)d_out, D);
        gram_fp8_kernel<<<T, THREADS, 0, stream>>>(xq, targets, sub,
                                                   pr, pc, D);
        finalize_sym_kernel<<<N / 16, THREADS, 0, stream>>>(
            pr, pc, (float*)d_out, N, nbx);
    } else {
        // Fallback (144 KB ws): fp32 path, known-good from round 1.
        float* inv_norm = (float*)d_ws;
        float* acc = inv_norm + N;
        hipMemsetAsync(acc, 0, (size_t)N * 8 * sizeof(float), stream);
        row_inv_norm_kernel<<<N, THREADS, 0, stream>>>(x, inv_norm, D);
        dist_loss_kernel<<<nbx * nbx, THREADS, 0, stream>>>(
            x, targets, sub, inv_norm, acc, N, D);
        finalize_kernel<<<1, THREADS, 0, stream>>>(acc, (float*)d_out, N);
    }
}

// Round 7
// 161.741 us; speedup vs baseline: 1.0376x; 1.0376x over previous
//
#include <hip/hip_runtime.h>
#include <math.h>

#define THREADS 256
#define BM 128
#define QBK 64                    // fp8 K per iteration (64 B row slice)
#define EPSV 1e-5f
#define C1E 11.023176380641601f   // e^2.4
#define C2E 9.025013499434122f    // e^2.2
#define FP8_SCALE 256.0f          // power-of-2 row scale into e4m3 range
#define INV_SCALE2 1.52587890625e-5f   // 1/65536, exact

typedef float f32x4 __attribute__((ext_vector_type(4)));

// ---------------------------------------------------------------------------
// Kernel A (fp8 path): normalize row, scale by 256, convert to OCP e4m3.
// Also zero-inits d_out (block 0) so the separate memset launch is dropped.
// ---------------------------------------------------------------------------
__launch_bounds__(THREADS)
__global__ void norm_conv_fp8_kernel(const float* __restrict__ x,
                                     unsigned char* __restrict__ xq,
                                     float* __restrict__ out, int D) {
    const int row = blockIdx.x;
    const float4* x4 = (const float4*)(x + (size_t)row * D);
    const int tid = threadIdx.x;
    if (row == 0 && tid == 0) out[0] = 0.f;

    float s = 0.f;
    for (int b = tid * 2; b * 4 < D; b += THREADS * 2) {
        float4 v0 = x4[b];
        float4 v1 = x4[b + 1];
        s += v0.x * v0.x + v0.y * v0.y + v0.z * v0.z + v0.w * v0.w
           + v1.x * v1.x + v1.y * v1.y + v1.z * v1.z + v1.w * v1.w;
    }
#pragma unroll
    for (int off = 32; off > 0; off >>= 1) s += __shfl_down(s, off, 64);
    __shared__ float red[THREADS / 64 + 1];
    if ((tid & 63) == 0) red[tid >> 6] = s;
    __syncthreads();
    if (tid == 0) {
        float tot = 0.f;
#pragma unroll
        for (int w = 0; w < THREADS / 64; ++w) tot += red[w];
        red[THREADS / 64] = FP8_SCALE / fmaxf(sqrtf(tot), 1e-12f);
    }
    __syncthreads();
    const float sc = red[THREADS / 64];

    int2* outq = (int2*)(xq + (size_t)row * D);
    for (int b = tid * 2; b * 4 < D; b += THREADS * 2) {
        float4 v0 = x4[b];
        float4 v1 = x4[b + 1];
        int lo = __builtin_amdgcn_cvt_pk_fp8_f32(v0.x * sc, v0.y * sc, 0, 0);
        lo = __builtin_amdgcn_cvt_pk_fp8_f32(v0.z * sc, v0.w * sc, lo, 1);
        int hi = __builtin_amdgcn_cvt_pk_fp8_f32(v1.x * sc, v1.y * sc, 0, 0);
        hi = __builtin_amdgcn_cvt_pk_fp8_f32(v1.z * sc, v1.w * sc, hi, 1);
        int2 o; o.x = lo; o.y = hi;
        outq[b >> 1] = o;
    }
}

// Plain inv-norm (fallback path).
__global__ void row_inv_norm_kernel(const float* __restrict__ x,
                                    float* __restrict__ inv_norm, int D) {
    const int row = blockIdx.x;
    const float4* x4 = (const float4*)(x + (size_t)row * D);
    const int nf4 = D >> 2;
    float s = 0.f;
    for (int i = threadIdx.x; i < nf4; i += THREADS) {
        float4 v = x4[i];
        s += v.x * v.x + v.y * v.y + v.z * v.z + v.w * v.w;
    }
#pragma unroll
    for (int off = 32; off > 0; off >>= 1) s += __shfl_down(s, off, 64);
    __shared__ float red[THREADS / 64];
    if ((threadIdx.x & 63) == 0) red[threadIdx.x >> 6] = s;
    __syncthreads();
    if (threadIdx.x == 0) {
        float tot = 0.f;
#pragma unroll
        for (int w = 0; w < THREADS / 64; ++w) tot += red[w];
        inv_norm[row] = 1.0f / fmaxf(sqrtf(tot), 1e-12f);
    }
}

#define GLDS16(g, l)                                                          \
    __builtin_amdgcn_global_load_lds(                                         \
        (const __attribute__((address_space(1))) unsigned int*)(g),           \
        (__attribute__((address_space(3))) unsigned int*)(l), 16, 0, 0)

// ---------------------------------------------------------------------------
// Kernel B: SYMMETRIC fp8 Gram. R7 = R5 minus the dd write-back.
// Spill ledger: R4 (124 arch, 2-pass): clean. R5 (84 arch, 2-pass): spills
// ~37 f32. R6 (84 arch, fused): spills ~70. Diagnosis: pass 1's
// `accv[mi][ni][r] = dd` writes VALU results element-wise into the ACC-reg
// array -> allocator promotes the whole 64-f32 accv into the ARCH half with
// liveness spanning both passes -> arch demand ~110 > 84 -> spill. FIX:
// accv stays READ-ONLY in ACC regs; pass 2 recomputes dd from the dot
// (fmaf+sqrt, 64 cheap ops/thread vs 36 MB scratch traffic).
// Config: __launch_bounds__(256,3) -> 3 blocks/CU (528 <= 768, single
// round); triple-buffered staging (3 x 16 KB LDS) with counted vmcnt:
// per iter: s_waitcnt vmcnt(4) -> s_barrier -> stage tile t+2 ->
// ds_read + 32 MFMA (loads get ~2 iterations to land, no mid-loop drain).
// SUCCESS CRITERION: WRITE_SIZE == 4224 KB (real pr/pc stores only).
// Staging swizzle (QBK=64): LDS slot q of row r holds global chunk
// q ^ ((r>>1)&3); fragment read of k-slot sl=ks*4+quad lives at byte
// r*64 + (((sl>>1)^((r>>1)&3))<<4) + ((sl&1)<<3); ks=1 is ks=0 ^ 32.
// vals: 0 s_pos_intra 1 cnt_pi 2 s_pos_cross 3 cnt_pc
//       4 DE_neg_intra 5 E_neg_intra 6 DE_neg_cross 7 E_neg_cross
// ---------------------------------------------------------------------------
__launch_bounds__(THREADS, 3)
__global__ void gram_fp8_kernel(const unsigned char* __restrict__ xq,
                                const int* __restrict__ targets,
                                const int* __restrict__ sub,
                                float* __restrict__ pr,
                                float* __restrict__ pc,
                                int D) {
    __shared__ unsigned char As[3][BM * QBK];   // 3 x 8 KB
    __shared__ unsigned char Bs[3][BM * QBK];   // 3 x 8 KB

    // XCD-chunked tile mapping (bijective: gridDim.x % 8 == 0).
    int tk = blockIdx.x;
    if ((gridDim.x & 7) == 0) {
        const int per = gridDim.x >> 3;
        tk = (tk & 7) * per + (tk >> 3);
    }

    // Triangular decode: tk = bx*(bx+1)/2 + by, by <= bx.
    int bx = (int)((sqrtf(8.0f * tk + 1.0f) - 1.0f) * 0.5f);
    while ((bx + 1) * (bx + 2) / 2 <= tk) ++bx;
    while (bx * (bx + 1) / 2 > tk) --bx;
    const int by = tk - bx * (bx + 1) / 2;

    const int tid = threadIdx.x;
    const int w = tid >> 6;          // wave 0..3
    const int lane = tid & 63;
    const int wm = w >> 1;           // row half (0..1)
    const int wn = w & 1;            // col half (0..1)
    const int quad = lane >> 4;
    const int cl = lane & 15;

    const int rowA0 = by * BM;
    const int colB0 = bx * BM;

    // Staging: per matrix 512 chunks of 16B (128 rows x 4); thread covers
    // chunks c = l*256 + tid, l=0..1. r = c>>2 = l*64 + (tid>>2);
    // source slot qs = (tid&3) ^ ((r>>1)&3) = (tid&3) ^ ((tid>>3)&3).
    const int qs = (tid & 3) ^ ((tid >> 3) & 3);
    const unsigned char* sA[2];
    const unsigned char* sB[2];
    int dof[2];
#pragma unroll
    for (int l = 0; l < 2; ++l) {
        const int r = l * 64 + (tid >> 2);
        sA[l] = xq + (size_t)(rowA0 + r) * D + qs * 16;
        sB[l] = xq + (size_t)(colB0 + r) * D + qs * 16;
        dof[l] = (l * 256 + w * 64) * 16;   // wave-uniform byte base
    }

    // Fragment byte offsets for ks=0; ks=1 = ^32 (chunk bit1 flips).
    int aoff[4], boff[4];
#pragma unroll
    for (int mi = 0; mi < 4; ++mi) {
        const int ar = wm * 64 + mi * 16 + cl;
        aoff[mi] = ar * QBK + (((quad >> 1) ^ ((ar >> 1) & 3)) << 4)
                 + ((quad & 1) << 3);
    }
#pragma unroll
    for (int ni = 0; ni < 4; ++ni) {
        const int br = wn * 64 + ni * 16 + cl;
        boff[ni] = br * QBK + (((quad >> 1) ^ ((br >> 1) & 3)) << 4)
                 + ((quad & 1) << 3);
    }

    f32x4 accv[4][4];
#pragma unroll
    for (int mi = 0; mi < 4; ++mi)
#pragma unroll
        for (int ni = 0; ni < 4; ++ni) accv[mi][ni] = (f32x4)(0.f);

    const int nIter = D / QBK;

    // Prologue: stage tiles 0,1 into bufs 0,1 (8 vmem/wave outstanding).
#pragma unroll
    for (int l = 0; l < 2; ++l) {
        GLDS16(sA[l], &As[0][0] + dof[l]);
        GLDS16(sB[l], &Bs[0][0] + dof[l]);
    }
#pragma unroll
    for (int l = 0; l < 2; ++l) {
        GLDS16(sA[l] + QBK, &As[1][0] + dof[l]);
        GLDS16(sB[l] + QBK, &Bs[1][0] + dof[l]);
    }

    int cs = 0;          // t % 3
    int ps = 2;          // (t+2) % 3
    for (int t = 0; t < nIter; ++t) {
        // Tile t's 4 loads done; tile t+1's 4 may remain in flight.
        if (t + 1 < nIter)
            asm volatile("s_waitcnt vmcnt(4)" ::: "memory");
        else
            asm volatile("s_waitcnt vmcnt(0)" ::: "memory");
        __builtin_amdgcn_s_barrier();

        if (t + 2 < nIter) {
            const int kb = (t + 2) * QBK;
#pragma unroll
            for (int l = 0; l < 2; ++l) {
                GLDS16(sA[l] + kb, &As[ps][0] + dof[l]);
                GLDS16(sB[l] + kb, &Bs[ps][0] + dof[l]);
            }
        }

        const unsigned char* Ac = &As[cs][0];
        const unsigned char* Bc = &Bs[cs][0];
        long af[4], bf[4];
#pragma unroll
        for (int mi = 0; mi < 4; ++mi)
            af[mi] = *(const long*)(Ac + aoff[mi]);
#pragma unroll
        for (int ni = 0; ni < 4; ++ni)
            bf[ni] = *(const long*)(Bc + boff[ni]);
#pragma unroll
        for (int mi = 0; mi < 4; ++mi)
#pragma unroll
            for (int ni = 0; ni < 4; ++ni)
                accv[mi][ni] = __builtin_amdgcn_mfma_f32_16x16x32_fp8_fp8(
                    af[mi], bf[ni], accv[mi][ni], 0, 0, 0);
#pragma unroll
        for (int mi = 0; mi < 4; ++mi)
            af[mi] = *(const long*)(Ac + (aoff[mi] ^ 32));
#pragma unroll
        for (int ni = 0; ni < 4; ++ni)
            bf[ni] = *(const long*)(Bc + (boff[ni] ^ 32));
#pragma unroll
        for (int mi = 0; mi < 4; ++mi)
#pragma unroll
            for (int ni = 0; ni < 4; ++ni)
                accv[mi][ni] = __builtin_amdgcn_mfma_f32_16x16x32_fp8_fp8(
                    af[mi], bf[ni], accv[mi][ni], 0, 0, 0);

        cs = (cs == 2) ? 0 : cs + 1;
        ps = (ps == 2) ? 0 : ps + 1;
    }

    // ---------------- epilogue pass 1: row partials ----------------
    // C/D map: col = cl, row = quad*4 + reg. Dots carry scale 65536.
    // accv is READ-ONLY from here on (stays in ACC regs; no write-back).
    int tj[4], sj[4];
#pragma unroll
    for (int ni = 0; ni < 4; ++ni) {
        const int gc = colB0 + wn * 64 + ni * 16 + cl;
        tj[ni] = targets[gc];
        sj[ni] = sub[gc];
    }

    float* rowp = (float*)&As[0][0];   // reuse buf0: [2][128][8] = 8 KB
#pragma unroll
    for (int mi = 0; mi < 4; ++mi) {
#pragma unroll
        for (int r = 0; r < 4; ++r) {
            const int rloc = wm * 64 + mi * 16 + quad * 4 + r;
            const int gi = rowA0 + rloc;
            const int ti = targets[gi];     // L1-hot broadcast
            const int si = sub[gi];

            float s0 = 0.f, s1 = 0.f, s2 = 0.f, s3 = 0.f;
            float s4 = 0.f, s5 = 0.f, s6 = 0.f, s7 = 0.f;
#pragma unroll
            for (int ni = 0; ni < 4; ++ni) {
                const int gj = colB0 + wn * 64 + ni * 16 + cl;
                const float d2 =
                    fmaf(-2.0f * INV_SCALE2, accv[mi][ni][r], 2.0f);
                const float dd = sqrtf(fmaxf(d2, 1e-12f));
                const bool same = (ti == tj[ni]);
                const bool intra = (si == sj[ni]);
                const bool pos = same && (gi != gj);
                const bool neg = !same;
                const float mg = intra ? 1.4f : 0.7f;
                const float v = fmaxf(dd - mg, 0.f);
                const float e = __expf(-dd);   // e^alpha folded in finalize
                const float de = dd * e;
                if (pos && intra)  { s0 += v;  s1 += 1.f; }
                if (pos && !intra) { s2 += v;  s3 += 1.f; }
                if (neg && intra)  { s4 += de; s5 += e; }
                if (neg && !intra) { s6 += de; s7 += e; }
            }
#pragma unroll
            for (int off = 1; off < 16; off <<= 1) {
                s0 += __shfl_xor(s0, off, 64);
                s1 += __shfl_xor(s1, off, 64);
                s2 += __shfl_xor(s2, off, 64);
                s3 += __shfl_xor(s3, off, 64);
                s4 += __shfl_xor(s4, off, 64);
                s5 += __shfl_xor(s5, off, 64);
                s6 += __shfl_xor(s6, off, 64);
                s7 += __shfl_xor(s7, off, 64);
            }
            if (cl == 0) {
                float* dst = rowp + ((wn << 7) + rloc) * 8;
                float4 p0 = {s0, s1, s2, s3};
                float4 p1 = {s4, s5, s6, s7};
                *(float4*)(dst) = p0;
                *(float4*)(dst + 4) = p1;
            }
        }
    }
    __syncthreads();
    {
        const size_t prbase = (size_t)tk * 1024;
        for (int i = tid; i < 1024; i += THREADS)
            pr[prbase + i] = rowp[i] + rowp[1024 + i];
    }

    // ------- epilogue pass 2: col partials (dd recomputed from dot) -------
    float* colp = (float*)&Bs[0][0];   // reuse buf0: [2][128][8] = 8 KB
#pragma unroll
    for (int ni = 0; ni < 4; ++ni) {
        const int gj = colB0 + wn * 64 + ni * 16 + cl;
        const int tjc = tj[ni];
        const int sjc = sj[ni];
        float s0 = 0.f, s1 = 0.f, s2 = 0.f, s3 = 0.f;
        float s4 = 0.f, s5 = 0.f, s6 = 0.f, s7 = 0.f;
#pragma unroll
        for (int mi = 0; mi < 4; ++mi) {
#pragma unroll
            for (int r = 0; r < 4; ++r) {
                const int gi = rowA0 + wm * 64 + mi * 16 + quad * 4 + r;
                const int ti = targets[gi];     // L1-hot reload
                const int si = sub[gi];
                const float d2 =
                    fmaf(-2.0f * INV_SCALE2, accv[mi][ni][r], 2.0f);
                const float dd = sqrtf(fmaxf(d2, 1e-12f));
                const bool same = (ti == tjc);
                const bool intra = (si == sjc);
                const bool pos = same && (gi != gj);
                const bool neg = !same;
                const float mg = intra ? 1.4f : 0.7f;
                const float v = fmaxf(dd - mg, 0.f);
                const float e = __expf(-dd);
                const float de = dd * e;
                if (pos && intra)  { s0 += v;  s1 += 1.f; }
                if (pos && !intra) { s2 += v;  s3 += 1.f; }
                if (neg && intra)  { s4 += de; s5 += e; }
                if (neg && !intra) { s6 += de; s7 += e; }
            }
        }
        s0 += __shfl_xor(s0, 16, 64); s0 += __shfl_xor(s0, 32, 64);
        s1 += __shfl_xor(s1, 16, 64); s1 += __shfl_xor(s1, 32, 64);
        s2 += __shfl_xor(s2, 16, 64); s2 += __shfl_xor(s2, 32, 64);
        s3 += __shfl_xor(s3, 16, 64); s3 += __shfl_xor(s3, 32, 64);
        s4 += __shfl_xor(s4, 16, 64); s4 += __shfl_xor(s4, 32, 64);
        s5 += __shfl_xor(s5, 16, 64); s5 += __shfl_xor(s5, 32, 64);
        s6 += __shfl_xor(s6, 16, 64); s6 += __shfl_xor(s6, 32, 64);
        s7 += __shfl_xor(s7, 16, 64); s7 += __shfl_xor(s7, 32, 64);
        if (lane < 16) {
            const int colloc = wn * 64 + ni * 16 + lane;
            float* dst = colp + ((wm << 7) + colloc) * 8;
            float4 p0 = {s0, s1, s2, s3};
            float4 p1 = {s4, s5, s6, s7};
            *(float4*)(dst) = p0;
            *(float4*)(dst + 4) = p1;
        }
    }
    __syncthreads();
    {
        const float om = (bx == by) ? 0.f : 1.f;   // diag: zero col side
        const size_t pcbase = (size_t)tk * 1024;
        for (int i = tid; i < 1024; i += THREADS)
            pc[pcbase + i] = (colp[i] + colp[1024 + i]) * om;
    }
}

// ---------------------------------------------------------------------------
// Kernel C: gather 33 slices per row (nbx-B from pr, B+1 from pc; the
// diagonal pc slice is pre-zeroed), combine ratios, global mean.
// ---------------------------------------------------------------------------
__global__ void finalize_sym_kernel(const float* __restrict__ pr,
                                    const float* __restrict__ pc,
                                    float* __restrict__ out, int N, int nbx) {
    const int tid = threadIdx.x;
    const int rloc16 = tid >> 4;
    const int st = tid & 15;
    const int i = blockIdx.x * 16 + rloc16;
    const int B = i >> 7;
    const int rl = i & 127;
    const int nrow = nbx - B;          // pr-slice count
    const int ntot = nbx + 1;          // total slices (one is zero)

    float a0 = 0.f, a1 = 0.f, a2 = 0.f, a3 = 0.f;
    float a4 = 0.f, a5 = 0.f, a6 = 0.f, a7 = 0.f;
    for (int s = st; s < ntot; s += 16) {
        const float* base;
        if (s < nrow) {
            const int bxx = B + s;
            base = pr + ((size_t)(bxx * (bxx + 1) / 2 + B) * 128 + rl) * 8;
        } else {
            const int byy = s - nrow;
            base = pc + ((size_t)(B * (B + 1) / 2 + byy) * 128 + rl) * 8;
        }
        float4 u0 = *(const float4*)(base);
        float4 u1 = *(const float4*)(base + 4);
        a0 += u0.x; a1 += u0.y; a2 += u0.z; a3 += u0.w;
        a4 += u1.x; a5 += u1.y; a6 += u1.z; a7 += u1.w;
    }
#pragma unroll
    for (int off = 1; off < 16; off <<= 1) {
        a0 += __shfl_xor(a0, off, 64);
        a1 += __shfl_xor(a1, off, 64);
        a2 += __shfl_xor(a2, off, 64);
        a3 += __shfl_xor(a3, off, 64);
        a4 += __shfl_xor(a4, off, 64);
        a5 += __shfl_xor(a5, off, 64);
        a6 += __shfl_xor(a6, off, 64);
        a7 += __shfl_xor(a7, off, 64);
    }
    __shared__ float lred[16];
    if (st == 0) {
        const float l = a0 / (a1 + EPSV) + a2 / (a3 + EPSV)
            + (C1E * fmaf(2.4f, a5, -a4)) / (C1E * a5 + EPSV)
            + (C2E * fmaf(2.2f, a7, -a6)) / (C2E * a7 + EPSV);
        lred[rloc16] = l;
    }
    __syncthreads();
    if (tid == 0) {
        float tot = 0.f;
#pragma unroll
        for (int k2 = 0; k2 < 16; ++k2) tot += lred[k2];
        atomicAdd(out, tot / (float)N);
    }
}

// ---------------------------------------------------------------------------
// Fallback path (144 KB ws): fp32 tile GEMM + atomic epilogue (R1, known-good)
// ---------------------------------------------------------------------------
__launch_bounds__(THREADS, 2)
__global__ void dist_loss_kernel(const float* __restrict__ x,
                                 const int* __restrict__ targets,
                                 const int* __restrict__ sub,
                                 const float* __restrict__ inv_norm,
                                 float* __restrict__ acc,
                                 int N, int D) {
    __shared__ float Asf[16][128];
    __shared__ float Bsf[16][128];

    const int nbx = N / 128;
    const int bx = blockIdx.x % nbx;
    const int by = blockIdx.x / nbx;
    const int tid = threadIdx.x;
    const int tx = tid & 15;
    const int ty = tid >> 4;
    const int rowA0 = by * 128;
    const int colB0 = bx * 128;
    const float* Abase = x + (size_t)rowA0 * D;
    const float* Bbase = x + (size_t)colB0 * D;

    float accv[8][8];
#pragma unroll
    for (int r = 0; r < 8; ++r)
#pragma unroll
        for (int c = 0; c < 8; ++c) accv[r][c] = 0.f;

    for (int kb = 0; kb < D; kb += 16) {
#pragma unroll
        for (int l = 0; l < 2; ++l) {
            const int f = tid + l * THREADS;
            const int row = f >> 2;
            const int kq = (f & 3) << 2;
            float4 va = *(const float4*)(Abase + (size_t)row * D + kb + kq);
            float4 vb = *(const float4*)(Bbase + (size_t)row * D + kb + kq);
            Asf[kq + 0][row] = va.x; Asf[kq + 1][row] = va.y;
            Asf[kq + 2][row] = va.z; Asf[kq + 3][row] = va.w;
            Bsf[kq + 0][row] = vb.x; Bsf[kq + 1][row] = vb.y;
            Bsf[kq + 2][row] = vb.z; Bsf[kq + 3][row] = vb.w;
        }
        __syncthreads();
#pragma unroll
        for (int k = 0; k < 16; ++k) {
            float4 a0 = *(const float4*)&Asf[k][ty * 8];
            float4 a1 = *(const float4*)&Asf[k][ty * 8 + 4];
            float4 b0 = *(const float4*)&Bsf[k][tx * 8];
            float4 b1 = *(const float4*)&Bsf[k][tx * 8 + 4];
            float ar[8] = {a0.x, a0.y, a0.z, a0.w, a1.x, a1.y, a1.z, a1.w};
            float br[8] = {b0.x, b0.y, b0.z, b0.w, b1.x, b1.y, b1.z, b1.w};
#pragma unroll
            for (int r = 0; r < 8; ++r)
#pragma unroll
                for (int c = 0; c < 8; ++c)
                    accv[r][c] = fmaf(ar[r], br[c], accv[r][c]);
        }
        __syncthreads();
    }

    const int row_base = rowA0 + ty * 8;
    const int col_base = colB0 + tx * 8;
    int tjc[8], sjc[8];
    float invj[8];
#pragma unroll
    for (int c = 0; c < 8; ++c) {
        tjc[c] = targets[col_base + c];
        sjc[c] = sub[col_base + c];
        invj[c] = inv_norm[col_base + c];
    }
#pragma unroll
    for (int r = 0; r < 8; ++r) {
        const int gi = row_base + r;
        const int ti = targets[gi];
        const int si = sub[gi];
        const float invi = inv_norm[gi];
        float s0 = 0.f, s1 = 0.f, s2 = 0.f, s3 = 0.f;
        float s4 = 0.f, s5 = 0.f, s6 = 0.f, s7 = 0.f;
#pragma unroll
        for (int c = 0; c < 8; ++c) {
            const int gj = col_base + c;
            const float dot = accv[r][c] * invi * invj[c];
            const float dd = sqrtf(fmaxf(2.f - 2.f * dot, 1e-12f));
            const bool same = (ti == tjc[c]);
            const bool intra = (si == sjc[c]);
            const bool pos = same && (gi != gj);
            const bool neg = !same;
            const float df = (intra ? 2.4f : 2.2f) - dd;
            const float wgt = __expf(df);
            const float v = fmaxf(dd - (intra ? 1.4f : 0.7f), 0.f);
            if (pos && intra)  { s0 += v; s1 += 1.f; }
            if (pos && !intra) { s2 += v; s3 += 1.f; }
            if (neg && intra)  { s4 += df * wgt; s5 += wgt; }
            if (neg && !intra) { s6 += df * wgt; s7 += wgt; }
        }
#pragma unroll
        for (int off = 1; off < 16; off <<= 1) {
            s0 += __shfl_xor(s0, off, 64);
            s1 += __shfl_xor(s1, off, 64);
            s2 += __shfl_xor(s2, off, 64);
            s3 += __shfl_xor(s3, off, 64);
            s4 += __shfl_xor(s4, off, 64);
            s5 += __shfl_xor(s5, off, 64);
            s6 += __shfl_xor(s6, off, 64);
            s7 += __shfl_xor(s7, off, 64);
        }
        if (tx == 0) {
            float* a = acc + (size_t)gi * 8;
            atomicAdd(a + 0, s0); atomicAdd(a + 1, s1);
            atomicAdd(a + 2, s2); atomicAdd(a + 3, s3);
            atomicAdd(a + 4, s4); atomicAdd(a + 5, s5);
            atomicAdd(a + 6, s6); atomicAdd(a + 7, s7);
        }
    }
}

__global__ void finalize_kernel(const float* __restrict__ acc,
                                float* __restrict__ out, int N) {
    float s = 0.f;
    for (int i = threadIdx.x; i < N; i += THREADS) {
        const float* a = acc + (size_t)i * 8;
        s += a[0] / (a[1] + EPSV) + a[2] / (a[3] + EPSV)
           + a[4] / (a[5] + EPSV) + a[6] / (a[7] + EPSV);
    }
#pragma unroll
    for (int off = 32; off > 0; off >>= 1) s += __shfl_down(s, off, 64);
    __shared__ float red[THREADS / 64];
    if ((threadIdx.x & 63) == 0) red[threadIdx.x >> 6] = s;
    __syncthreads();
    if (threadIdx.x == 0) {
        float tot = 0.f;
#pragma unroll
        for (int w = 0; w < THREADS / 64; ++w) tot += red[w];
        out[0] = tot / (float)N;
    }
}

// ---------------------------------------------------------------------------
extern "C" void kernel_launch(void* const* d_in, const int* in_sizes, int n_in,
                              void* d_out, int out_size, void* d_ws, size_t ws_size,
                              hipStream_t stream) {
    const float* x = (const float*)d_in[0];
    const int* targets = (const int*)d_in[1];
    const int* sub = (const int*)d_in[2];
    const int N = in_sizes[1];
    const int D = in_sizes[0] / N;

    const int nbx = N / BM;
    const int T = nbx * (nbx + 1) / 2;
    const size_t sliceB = (size_t)T * 128 * 8 * sizeof(float);
    const size_t need = (size_t)N * D + 2 * sliceB;   // fp8: N*D bytes

    if (ws_size >= need) {
        unsigned char* xq = (unsigned char*)d_ws;     // N*D fp8
        float* pr = (float*)((char*)d_ws + (size_t)N * D);
        float* pc = pr + (size_t)T * 128 * 8;

        norm_conv_fp8_kernel<<<N, THREADS, 0, stream>>>(x, xq,
                                                        (float*)d_out, D);
        gram_fp8_kernel<<<T, THREADS, 0, stream>>>(xq, targets, sub,
                                                   pr, pc, D);
        finalize_sym_kernel<<<N / 16, THREADS, 0, stream>>>(
            pr, pc, (float*)d_out, N, nbx);
    } else {
        // Fallback (144 KB ws): fp32 path, known-good from round 1.
        float* inv_norm = (float*)d_ws;
        float* acc = inv_norm + N;
        hipMemsetAsync(acc, 0, (size_t)N * 8 * sizeof(float), stream);
        row_inv_norm_kernel<<<N, THREADS, 0, stream>>>(x, inv_norm, D);
        dist_loss_kernel<<<nbx * nbx, THREADS, 0, stream>>>(
            x, targets, sub, inv_norm, acc, N, D);
        finalize_kernel<<<1, THREADS, 0, stream>>>(acc, (float*)d_out, N);
    }
}

// Round 8
// 154.701 us; speedup vs baseline: 1.0848x; 1.0455x over previous
//
#include <hip/hip_runtime.h>
#include <math.h>

#define THREADS 256
#define BM 128
#define QBK 64                    // fp8 K per iteration (64 B row slice)
#define EPSV 1e-5f
#define C1E 11.023176380641601f   // e^2.4
#define C2E 9.025013499434122f    // e^2.2
#define FP8_SCALE 256.0f          // power-of-2 row scale into e4m3 range
#define INV_SCALE2 1.52587890625e-5f   // 1/65536, exact

typedef float f32x4 __attribute__((ext_vector_type(4)));

// ---------------------------------------------------------------------------
// Kernel A (fp8 path): normalize row, scale by 256, convert to OCP e4m3.
// Also zero-inits d_out (block 0) so the separate memset launch is dropped.
// ---------------------------------------------------------------------------
__launch_bounds__(THREADS)
__global__ void norm_conv_fp8_kernel(const float* __restrict__ x,
                                     unsigned char* __restrict__ xq,
                                     float* __restrict__ out, int D) {
    const int row = blockIdx.x;
    const float4* x4 = (const float4*)(x + (size_t)row * D);
    const int tid = threadIdx.x;
    if (row == 0 && tid == 0) out[0] = 0.f;

    float s = 0.f;
    for (int b = tid * 2; b * 4 < D; b += THREADS * 2) {
        float4 v0 = x4[b];
        float4 v1 = x4[b + 1];
        s += v0.x * v0.x + v0.y * v0.y + v0.z * v0.z + v0.w * v0.w
           + v1.x * v1.x + v1.y * v1.y + v1.z * v1.z + v1.w * v1.w;
    }
#pragma unroll
    for (int off = 32; off > 0; off >>= 1) s += __shfl_down(s, off, 64);
    __shared__ float red[THREADS / 64 + 1];
    if ((tid & 63) == 0) red[tid >> 6] = s;
    __syncthreads();
    if (tid == 0) {
        float tot = 0.f;
#pragma unroll
        for (int w = 0; w < THREADS / 64; ++w) tot += red[w];
        red[THREADS / 64] = FP8_SCALE / fmaxf(sqrtf(tot), 1e-12f);
    }
    __syncthreads();
    const float sc = red[THREADS / 64];

    int2* outq = (int2*)(xq + (size_t)row * D);
    for (int b = tid * 2; b * 4 < D; b += THREADS * 2) {
        float4 v0 = x4[b];
        float4 v1 = x4[b + 1];
        int lo = __builtin_amdgcn_cvt_pk_fp8_f32(v0.x * sc, v0.y * sc, 0, 0);
        lo = __builtin_amdgcn_cvt_pk_fp8_f32(v0.z * sc, v0.w * sc, lo, 1);
        int hi = __builtin_amdgcn_cvt_pk_fp8_f32(v1.x * sc, v1.y * sc, 0, 0);
        hi = __builtin_amdgcn_cvt_pk_fp8_f32(v1.z * sc, v1.w * sc, hi, 1);
        int2 o; o.x = lo; o.y = hi;
        outq[b >> 1] = o;
    }
}

// Plain inv-norm (fallback path).
__global__ void row_inv_norm_kernel(const float* __restrict__ x,
                                    float* __restrict__ inv_norm, int D) {
    const int row = blockIdx.x;
    const float4* x4 = (const float4*)(x + (size_t)row * D);
    const int nf4 = D >> 2;
    float s = 0.f;
    for (int i = threadIdx.x; i < nf4; i += THREADS) {
        float4 v = x4[i];
        s += v.x * v.x + v.y * v.y + v.z * v.z + v.w * v.w;
    }
#pragma unroll
    for (int off = 32; off > 0; off >>= 1) s += __shfl_down(s, off, 64);
    __shared__ float red[THREADS / 64];
    if ((threadIdx.x & 63) == 0) red[threadIdx.x >> 6] = s;
    __syncthreads();
    if (threadIdx.x == 0) {
        float tot = 0.f;
#pragma unroll
        for (int w = 0; w < THREADS / 64; ++w) tot += red[w];
        inv_norm[row] = 1.0f / fmaxf(sqrtf(tot), 1e-12f);
    }
}

#define GLDS16(g, l)                                                          \
    __builtin_amdgcn_global_load_lds(                                         \
        (const __attribute__((address_space(1))) unsigned int*)(g),           \
        (__attribute__((address_space(3))) unsigned int*)(l), 16, 0, 0)

// ---------------------------------------------------------------------------
// Kernel B: SYMMETRIC fp8 Gram. R8 = R7 + CSE fence in pass 2.
// Spill ledger: R4 (124 arch): clean. R5 (84 arch, dd write-back): spills
// ~37 f32. R7 (84 arch, dd "recomputed" in pass 2): IDENTICAL counters to
// R5 (VGPR 84, WRITE 40656, LDS-conflict 4441536) -> the compiler CSE'd the
// recomputation back into pass-1's values, recreating the 64-value
// cross-pass liveness. FIX: route pass-2's accv read through an empty
// inline-asm value barrier ("+v") so the expression is opaque -> genuine
// recompute (64 fmaf+sqrt+exp, ~1 us) -> no dd-derived value lives across
// the pass boundary -> per-pass working set ~50 arch <= 84.
// Config: __launch_bounds__(256,3) -> 3 blocks/CU (528 <= 768, single
// round); triple-buffered staging (3 x 16 KB LDS) with counted vmcnt:
// per iter: s_waitcnt vmcnt(4) -> s_barrier -> stage tile t+2 ->
// ds_read + 32 MFMA (loads get ~2 iterations to land, no mid-loop drain).
// SUCCESS CRITERION: WRITE_SIZE == 4224 KB (real pr/pc stores only).
// Staging swizzle (QBK=64): LDS slot q of row r holds global chunk
// q ^ ((r>>1)&3); fragment read of k-slot sl=ks*4+quad lives at byte
// r*64 + (((sl>>1)^((r>>1)&3))<<4) + ((sl&1)<<3); ks=1 is ks=0 ^ 32.
// vals: 0 s_pos_intra 1 cnt_pi 2 s_pos_cross 3 cnt_pc
//       4 DE_neg_intra 5 E_neg_intra 6 DE_neg_cross 7 E_neg_cross
// ---------------------------------------------------------------------------
__launch_bounds__(THREADS, 3)
__global__ void gram_fp8_kernel(const unsigned char* __restrict__ xq,
                                const int* __restrict__ targets,
                                const int* __restrict__ sub,
                                float* __restrict__ pr,
                                float* __restrict__ pc,
                                int D) {
    __shared__ unsigned char As[3][BM * QBK];   // 3 x 8 KB
    __shared__ unsigned char Bs[3][BM * QBK];   // 3 x 8 KB

    // XCD-chunked tile mapping (bijective: gridDim.x % 8 == 0).
    int tk = blockIdx.x;
    if ((gridDim.x & 7) == 0) {
        const int per = gridDim.x >> 3;
        tk = (tk & 7) * per + (tk >> 3);
    }

    // Triangular decode: tk = bx*(bx+1)/2 + by, by <= bx.
    int bx = (int)((sqrtf(8.0f * tk + 1.0f) - 1.0f) * 0.5f);
    while ((bx + 1) * (bx + 2) / 2 <= tk) ++bx;
    while (bx * (bx + 1) / 2 > tk) --bx;
    const int by = tk - bx * (bx + 1) / 2;

    const int tid = threadIdx.x;
    const int w = tid >> 6;          // wave 0..3
    const int lane = tid & 63;
    const int wm = w >> 1;           // row half (0..1)
    const int wn = w & 1;            // col half (0..1)
    const int quad = lane >> 4;
    const int cl = lane & 15;

    const int rowA0 = by * BM;
    const int colB0 = bx * BM;

    // Staging: per matrix 512 chunks of 16B (128 rows x 4); thread covers
    // chunks c = l*256 + tid, l=0..1. r = c>>2 = l*64 + (tid>>2);
    // source slot qs = (tid&3) ^ ((r>>1)&3) = (tid&3) ^ ((tid>>3)&3).
    const int qs = (tid & 3) ^ ((tid >> 3) & 3);
    const unsigned char* sA[2];
    const unsigned char* sB[2];
    int dof[2];
#pragma unroll
    for (int l = 0; l < 2; ++l) {
        const int r = l * 64 + (tid >> 2);
        sA[l] = xq + (size_t)(rowA0 + r) * D + qs * 16;
        sB[l] = xq + (size_t)(colB0 + r) * D + qs * 16;
        dof[l] = (l * 256 + w * 64) * 16;   // wave-uniform byte base
    }

    // Fragment byte offsets for ks=0; ks=1 = ^32 (chunk bit1 flips).
    int aoff[4], boff[4];
#pragma unroll
    for (int mi = 0; mi < 4; ++mi) {
        const int ar = wm * 64 + mi * 16 + cl;
        aoff[mi] = ar * QBK + (((quad >> 1) ^ ((ar >> 1) & 3)) << 4)
                 + ((quad & 1) << 3);
    }
#pragma unroll
    for (int ni = 0; ni < 4; ++ni) {
        const int br = wn * 64 + ni * 16 + cl;
        boff[ni] = br * QBK + (((quad >> 1) ^ ((br >> 1) & 3)) << 4)
                 + ((quad & 1) << 3);
    }

    f32x4 accv[4][4];
#pragma unroll
    for (int mi = 0; mi < 4; ++mi)
#pragma unroll
        for (int ni = 0; ni < 4; ++ni) accv[mi][ni] = (f32x4)(0.f);

    const int nIter = D / QBK;

    // Prologue: stage tiles 0,1 into bufs 0,1 (8 vmem/wave outstanding).
#pragma unroll
    for (int l = 0; l < 2; ++l) {
        GLDS16(sA[l], &As[0][0] + dof[l]);
        GLDS16(sB[l], &Bs[0][0] + dof[l]);
    }
#pragma unroll
    for (int l = 0; l < 2; ++l) {
        GLDS16(sA[l] + QBK, &As[1][0] + dof[l]);
        GLDS16(sB[l] + QBK, &Bs[1][0] + dof[l]);
    }

    int cs = 0;          // t % 3
    int ps = 2;          // (t+2) % 3
    for (int t = 0; t < nIter; ++t) {
        // Tile t's 4 loads done; tile t+1's 4 may remain in flight.
        if (t + 1 < nIter)
            asm volatile("s_waitcnt vmcnt(4)" ::: "memory");
        else
            asm volatile("s_waitcnt vmcnt(0)" ::: "memory");
        __builtin_amdgcn_s_barrier();

        if (t + 2 < nIter) {
            const int kb = (t + 2) * QBK;
#pragma unroll
            for (int l = 0; l < 2; ++l) {
                GLDS16(sA[l] + kb, &As[ps][0] + dof[l]);
                GLDS16(sB[l] + kb, &Bs[ps][0] + dof[l]);
            }
        }

        const unsigned char* Ac = &As[cs][0];
        const unsigned char* Bc = &Bs[cs][0];
        long af[4], bf[4];
#pragma unroll
        for (int mi = 0; mi < 4; ++mi)
            af[mi] = *(const long*)(Ac + aoff[mi]);
#pragma unroll
        for (int ni = 0; ni < 4; ++ni)
            bf[ni] = *(const long*)(Bc + boff[ni]);
#pragma unroll
        for (int mi = 0; mi < 4; ++mi)
#pragma unroll
            for (int ni = 0; ni < 4; ++ni)
                accv[mi][ni] = __builtin_amdgcn_mfma_f32_16x16x32_fp8_fp8(
                    af[mi], bf[ni], accv[mi][ni], 0, 0, 0);
#pragma unroll
        for (int mi = 0; mi < 4; ++mi)
            af[mi] = *(const long*)(Ac + (aoff[mi] ^ 32));
#pragma unroll
        for (int ni = 0; ni < 4; ++ni)
            bf[ni] = *(const long*)(Bc + (boff[ni] ^ 32));
#pragma unroll
        for (int mi = 0; mi < 4; ++mi)
#pragma unroll
            for (int ni = 0; ni < 4; ++ni)
                accv[mi][ni] = __builtin_amdgcn_mfma_f32_16x16x32_fp8_fp8(
                    af[mi], bf[ni], accv[mi][ni], 0, 0, 0);

        cs = (cs == 2) ? 0 : cs + 1;
        ps = (ps == 2) ? 0 : ps + 1;
    }

    // ---------------- epilogue pass 1: row partials ----------------
    // C/D map: col = cl, row = quad*4 + reg. Dots carry scale 65536.
    // accv is READ-ONLY from here on (stays in ACC regs; no write-back).
    int tj[4], sj[4];
#pragma unroll
    for (int ni = 0; ni < 4; ++ni) {
        const int gc = colB0 + wn * 64 + ni * 16 + cl;
        tj[ni] = targets[gc];
        sj[ni] = sub[gc];
    }

    float* rowp = (float*)&As[0][0];   // reuse buf0: [2][128][8] = 8 KB
#pragma unroll
    for (int mi = 0; mi < 4; ++mi) {
#pragma unroll
        for (int r = 0; r < 4; ++r) {
            const int rloc = wm * 64 + mi * 16 + quad * 4 + r;
            const int gi = rowA0 + rloc;
            const int ti = targets[gi];     // L1-hot broadcast
            const int si = sub[gi];

            float s0 = 0.f, s1 = 0.f, s2 = 0.f, s3 = 0.f;
            float s4 = 0.f, s5 = 0.f, s6 = 0.f, s7 = 0.f;
#pragma unroll
            for (int ni = 0; ni < 4; ++ni) {
                const int gj = colB0 + wn * 64 + ni * 16 + cl;
                const float d2 =
                    fmaf(-2.0f * INV_SCALE2, accv[mi][ni][r], 2.0f);
                const float dd = sqrtf(fmaxf(d2, 1e-12f));
                const bool same = (ti == tj[ni]);
                const bool intra = (si == sj[ni]);
                const bool pos = same && (gi != gj);
                const bool neg = !same;
                const float mg = intra ? 1.4f : 0.7f;
                const float v = fmaxf(dd - mg, 0.f);
                const float e = __expf(-dd);   // e^alpha folded in finalize
                const float de = dd * e;
                if (pos && intra)  { s0 += v;  s1 += 1.f; }
                if (pos && !intra) { s2 += v;  s3 += 1.f; }
                if (neg && intra)  { s4 += de; s5 += e; }
                if (neg && !intra) { s6 += de; s7 += e; }
            }
#pragma unroll
            for (int off = 1; off < 16; off <<= 1) {
                s0 += __shfl_xor(s0, off, 64);
                s1 += __shfl_xor(s1, off, 64);
                s2 += __shfl_xor(s2, off, 64);
                s3 += __shfl_xor(s3, off, 64);
                s4 += __shfl_xor(s4, off, 64);
                s5 += __shfl_xor(s5, off, 64);
                s6 += __shfl_xor(s6, off, 64);
                s7 += __shfl_xor(s7, off, 64);
            }
            if (cl == 0) {
                float* dst = rowp + ((wn << 7) + rloc) * 8;
                float4 p0 = {s0, s1, s2, s3};
                float4 p1 = {s4, s5, s6, s7};
                *(float4*)(dst) = p0;
                *(float4*)(dst + 4) = p1;
            }
        }
    }
    __syncthreads();
    {
        const size_t prbase = (size_t)tk * 1024;
        for (int i = tid; i < 1024; i += THREADS)
            pr[prbase + i] = rowp[i] + rowp[1024 + i];
    }

    // ------- epilogue pass 2: col partials (dd recomputed for real) -------
    // The asm "+v" makes the accv read opaque: defeats cross-pass CSE that
    // otherwise keeps 64 dd/e/de values live from pass 1 (R5==R7 evidence).
    float* colp = (float*)&Bs[0][0];   // reuse buf0: [2][128][8] = 8 KB
#pragma unroll
    for (int ni = 0; ni < 4; ++ni) {
        const int gj = colB0 + wn * 64 + ni * 16 + cl;
        const int tjc = tj[ni];
        const int sjc = sj[ni];
        float s0 = 0.f, s1 = 0.f, s2 = 0.f, s3 = 0.f;
        float s4 = 0.f, s5 = 0.f, s6 = 0.f, s7 = 0.f;
#pragma unroll
        for (int mi = 0; mi < 4; ++mi) {
#pragma unroll
            for (int r = 0; r < 4; ++r) {
                const int gi = rowA0 + wm * 64 + mi * 16 + quad * 4 + r;
                const int ti = targets[gi];     // L1-hot reload
                const int si = sub[gi];
                float dot = accv[mi][ni][r];
                asm volatile("" : "+v"(dot));   // CSE fence (see header)
                const float d2 = fmaf(-2.0f * INV_SCALE2, dot, 2.0f);
                const float dd = sqrtf(fmaxf(d2, 1e-12f));
                const bool same = (ti == tjc);
                const bool intra = (si == sjc);
                const bool pos = same && (gi != gj);
                const bool neg = !same;
                const float mg = intra ? 1.4f : 0.7f;
                const float v = fmaxf(dd - mg, 0.f);
                const float e = __expf(-dd);
                const float de = dd * e;
                if (pos && intra)  { s0 += v;  s1 += 1.f; }
                if (pos && !intra) { s2 += v;  s3 += 1.f; }
                if (neg && intra)  { s4 += de; s5 += e; }
                if (neg && !intra) { s6 += de; s7 += e; }
            }
        }
        s0 += __shfl_xor(s0, 16, 64); s0 += __shfl_xor(s0, 32, 64);
        s1 += __shfl_xor(s1, 16, 64); s1 += __shfl_xor(s1, 32, 64);
        s2 += __shfl_xor(s2, 16, 64); s2 += __shfl_xor(s2, 32, 64);
        s3 += __shfl_xor(s3, 16, 64); s3 += __shfl_xor(s3, 32, 64);
        s4 += __shfl_xor(s4, 16, 64); s4 += __shfl_xor(s4, 32, 64);
        s5 += __shfl_xor(s5, 16, 64); s5 += __shfl_xor(s5, 32, 64);
        s6 += __shfl_xor(s6, 16, 64); s6 += __shfl_xor(s6, 32, 64);
        s7 += __shfl_xor(s7, 16, 64); s7 += __shfl_xor(s7, 32, 64);
        if (lane < 16) {
            const int colloc = wn * 64 + ni * 16 + lane;
            float* dst = colp + ((wm << 7) + colloc) * 8;
            float4 p0 = {s0, s1, s2, s3};
            float4 p1 = {s4, s5, s6, s7};
            *(float4*)(dst) = p0;
            *(float4*)(dst + 4) = p1;
        }
    }
    __syncthreads();
    {
        const float om = (bx == by) ? 0.f : 1.f;   // diag: zero col side
        const size_t pcbase = (size_t)tk * 1024;
        for (int i = tid; i < 1024; i += THREADS)
            pc[pcbase + i] = (colp[i] + colp[1024 + i]) * om;
    }
}

// ---------------------------------------------------------------------------
// Kernel C: gather 33 slices per row (nbx-B from pr, B+1 from pc; the
// diagonal pc slice is pre-zeroed), combine ratios, global mean.
// ---------------------------------------------------------------------------
__global__ void finalize_sym_kernel(const float* __restrict__ pr,
                                    const float* __restrict__ pc,
                                    float* __restrict__ out, int N, int nbx) {
    const int tid = threadIdx.x;
    const int rloc16 = tid >> 4;
    const int st = tid & 15;
    const int i = blockIdx.x * 16 + rloc16;
    const int B = i >> 7;
    const int rl = i & 127;
    const int nrow = nbx - B;          // pr-slice count
    const int ntot = nbx + 1;          // total slices (one is zero)

    float a0 = 0.f, a1 = 0.f, a2 = 0.f, a3 = 0.f;
    float a4 = 0.f, a5 = 0.f, a6 = 0.f, a7 = 0.f;
    for (int s = st; s < ntot; s += 16) {
        const float* base;
        if (s < nrow) {
            const int bxx = B + s;
            base = pr + ((size_t)(bxx * (bxx + 1) / 2 + B) * 128 + rl) * 8;
        } else {
            const int byy = s - nrow;
            base = pc + ((size_t)(B * (B + 1) / 2 + byy) * 128 + rl) * 8;
        }
        float4 u0 = *(const float4*)(base);
        float4 u1 = *(const float4*)(base + 4);
        a0 += u0.x; a1 += u0.y; a2 += u0.z; a3 += u0.w;
        a4 += u1.x; a5 += u1.y; a6 += u1.z; a7 += u1.w;
    }
#pragma unroll
    for (int off = 1; off < 16; off <<= 1) {
        a0 += __shfl_xor(a0, off, 64);
        a1 += __shfl_xor(a1, off, 64);
        a2 += __shfl_xor(a2, off, 64);
        a3 += __shfl_xor(a3, off, 64);
        a4 += __shfl_xor(a4, off, 64);
        a5 += __shfl_xor(a5, off, 64);
        a6 += __shfl_xor(a6, off, 64);
        a7 += __shfl_xor(a7, off, 64);
    }
    __shared__ float lred[16];
    if (st == 0) {
        const float l = a0 / (a1 + EPSV) + a2 / (a3 + EPSV)
            + (C1E * fmaf(2.4f, a5, -a4)) / (C1E * a5 + EPSV)
            + (C2E * fmaf(2.2f, a7, -a6)) / (C2E * a7 + EPSV);
        lred[rloc16] = l;
    }
    __syncthreads();
    if (tid == 0) {
        float tot = 0.f;
#pragma unroll
        for (int k2 = 0; k2 < 16; ++k2) tot += lred[k2];
        atomicAdd(out, tot / (float)N);
    }
}

// ---------------------------------------------------------------------------
// Fallback path (144 KB ws): fp32 tile GEMM + atomic epilogue (R1, known-good)
// ---------------------------------------------------------------------------
__launch_bounds__(THREADS, 2)
__global__ void dist_loss_kernel(const float* __restrict__ x,
                                 const int* __restrict__ targets,
                                 const int* __restrict__ sub,
                                 const float* __restrict__ inv_norm,
                                 float* __restrict__ acc,
                                 int N, int D) {
    __shared__ float Asf[16][128];
    __shared__ float Bsf[16][128];

    const int nbx = N / 128;
    const int bx = blockIdx.x % nbx;
    const int by = blockIdx.x / nbx;
    const int tid = threadIdx.x;
    const int tx = tid & 15;
    const int ty = tid >> 4;
    const int rowA0 = by * 128;
    const int colB0 = bx * 128;
    const float* Abase = x + (size_t)rowA0 * D;
    const float* Bbase = x + (size_t)colB0 * D;

    float accv[8][8];
#pragma unroll
    for (int r = 0; r < 8; ++r)
#pragma unroll
        for (int c = 0; c < 8; ++c) accv[r][c] = 0.f;

    for (int kb = 0; kb < D; kb += 16) {
#pragma unroll
        for (int l = 0; l < 2; ++l) {
            const int f = tid + l * THREADS;
            const int row = f >> 2;
            const int kq = (f & 3) << 2;
            float4 va = *(const float4*)(Abase + (size_t)row * D + kb + kq);
            float4 vb = *(const float4*)(Bbase + (size_t)row * D + kb + kq);
            Asf[kq + 0][row] = va.x; Asf[kq + 1][row] = va.y;
            Asf[kq + 2][row] = va.z; Asf[kq + 3][row] = va.w;
            Bsf[kq + 0][row] = vb.x; Bsf[kq + 1][row] = vb.y;
            Bsf[kq + 2][row] = vb.z; Bsf[kq + 3][row] = vb.w;
        }
        __syncthreads();
#pragma unroll
        for (int k = 0; k < 16; ++k) {
            float4 a0 = *(const float4*)&Asf[k][ty * 8];
            float4 a1 = *(const float4*)&Asf[k][ty * 8 + 4];
            float4 b0 = *(const float4*)&Bsf[k][tx * 8];
            float4 b1 = *(const float4*)&Bsf[k][tx * 8 + 4];
            float ar[8] = {a0.x, a0.y, a0.z, a0.w, a1.x, a1.y, a1.z, a1.w};
            float br[8] = {b0.x, b0.y, b0.z, b0.w, b1.x, b1.y, b1.z, b1.w};
#pragma unroll
            for (int r = 0; r < 8; ++r)
#pragma unroll
                for (int c = 0; c < 8; ++c)
                    accv[r][c] = fmaf(ar[r], br[c], accv[r][c]);
        }
        __syncthreads();
    }

    const int row_base = rowA0 + ty * 8;
    const int col_base = colB0 + tx * 8;
    int tjc[8], sjc[8];
    float invj[8];
#pragma unroll
    for (int c = 0; c < 8; ++c) {
        tjc[c] = targets[col_base + c];
        sjc[c] = sub[col_base + c];
        invj[c] = inv_norm[col_base + c];
    }
#pragma unroll
    for (int r = 0; r < 8; ++r) {
        const int gi = row_base + r;
        const int ti = targets[gi];
        const int si = sub[gi];
        const float invi = inv_norm[gi];
        float s0 = 0.f, s1 = 0.f, s2 = 0.f, s3 = 0.f;
        float s4 = 0.f, s5 = 0.f, s6 = 0.f, s7 = 0.f;
#pragma unroll
        for (int c = 0; c < 8; ++c) {
            const int gj = col_base + c;
            const float dot = accv[r][c] * invi * invj[c];
            const float dd = sqrtf(fmaxf(2.f - 2.f * dot, 1e-12f));
            const bool same = (ti == tjc[c]);
            const bool intra = (si == sjc[c]);
            const bool pos = same && (gi != gj);
            const bool neg = !same;
            const float df = (intra ? 2.4f : 2.2f) - dd;
            const float wgt = __expf(df);
            const float v = fmaxf(dd - (intra ? 1.4f : 0.7f), 0.f);
            if (pos && intra)  { s0 += v; s1 += 1.f; }
            if (pos && !intra) { s2 += v; s3 += 1.f; }
            if (neg && intra)  { s4 += df * wgt; s5 += wgt; }
            if (neg && !intra) { s6 += df * wgt; s7 += wgt; }
        }
#pragma unroll
        for (int off = 1; off < 16; off <<= 1) {
            s0 += __shfl_xor(s0, off, 64);
            s1 += __shfl_xor(s1, off, 64);
            s2 += __shfl_xor(s2, off, 64);
            s3 += __shfl_xor(s3, off, 64);
            s4 += __shfl_xor(s4, off, 64);
            s5 += __shfl_xor(s5, off, 64);
            s6 += __shfl_xor(s6, off, 64);
            s7 += __shfl_xor(s7, off, 64);
        }
        if (tx == 0) {
            float* a = acc + (size_t)gi * 8;
            atomicAdd(a + 0, s0); atomicAdd(a + 1, s1);
            atomicAdd(a + 2, s2); atomicAdd(a + 3, s3);
            atomicAdd(a + 4, s4); atomicAdd(a + 5, s5);
            atomicAdd(a + 6, s6); atomicAdd(a + 7, s7);
        }
    }
}

__global__ void finalize_kernel(const float* __restrict__ acc,
                                float* __restrict__ out, int N) {
    float s = 0.f;
    for (int i = threadIdx.x; i < N; i += THREADS) {
        const float* a = acc + (size_t)i * 8;
        s += a[0] / (a[1] + EPSV) + a[2] / (a[3] + EPSV)
           + a[4] / (a[5] + EPSV) + a[6] / (a[7] + EPSV);
    }
#pragma unroll
    for (int off = 32; off > 0; off >>= 1) s += __shfl_down(s, off, 64);
    __shared__ float red[THREADS / 64];
    if ((threadIdx.x & 63) == 0) red[threadIdx.x >> 6] = s;
    __syncthreads();
    if (threadIdx.x == 0) {
        float tot = 0.f;
#pragma unroll
        for (int w = 0; w < THREADS / 64; ++w) tot += red[w];
        out[0] = tot / (float)N;
    }
}

// ---------------------------------------------------------------------------
extern "C" void kernel_launch(void* const* d_in, const int* in_sizes, int n_in,
                              void* d_out, int out_size, void* d_ws, size_t ws_size,
                              hipStream_t stream) {
    const float* x = (const float*)d_in[0];
    const int* targets = (const int*)d_in[1];
    const int* sub = (const int*)d_in[2];
    const int N = in_sizes[1];
    const int D = in_sizes[0] / N;

    const int nbx = N / BM;
    const int T = nbx * (nbx + 1) / 2;
    const size_t sliceB = (size_t)T * 128 * 8 * sizeof(float);
    const size_t need = (size_t)N * D + 2 * sliceB;   // fp8: N*D bytes

    if (ws_size >= need) {
        unsigned char* xq = (unsigned char*)d_ws;     // N*D fp8
        float* pr = (float*)((char*)d_ws + (size_t)N * D);
        float* pc = pr + (size_t)T * 128 * 8;

        norm_conv_fp8_kernel<<<N, THREADS, 0, stream>>>(x, xq,
                                                        (float*)d_out, D);
        gram_fp8_kernel<<<T, THREADS, 0, stream>>>(xq, targets, sub,
                                                   pr, pc, D);
        finalize_sym_kernel<<<N / 16, THREADS, 0, stream>>>(
            pr, pc, (float*)d_out, N, nbx);
    } else {
        // Fallback (144 KB ws): fp32 path, known-good from round 1.
        float* inv_norm = (float*)d_ws;
        float* acc = inv_norm + N;
        hipMemsetAsync(acc, 0, (size_t)N * 8 * sizeof(float), stream);
        row_inv_norm_kernel<<<N, THREADS, 0, stream>>>(x, inv_norm, D);
        dist_loss_kernel<<<nbx * nbx, THREADS, 0, stream>>>(
            x, targets, sub, inv_norm, acc, N, D);
        finalize_kernel<<<1, THREADS, 0, stream>>>(acc, (float*)d_out, N);
    }
}

// Round 9
// 152.906 us; speedup vs baseline: 1.0975x; 1.0117x over previous
//
#include <hip/hip_runtime.h>
#include <math.h>

#define THREADS 256
#define BM 128
#define QBK 64                    // fp8 K per iteration (64 B row slice)
#define EPSV 1e-5f
#define C1E 11.023176380641601f   // e^2.4
#define C2E 9.025013499434122f    // e^2.2
#define FP8_SCALE 256.0f          // power-of-2 row scale into e4m3 range
#define INV_SCALE2 1.52587890625e-5f   // 1/65536, exact

typedef float f32x4 __attribute__((ext_vector_type(4)));

// ---------------------------------------------------------------------------
// Kernel A (fp8 path): normalize row, scale by 256, convert to OCP e4m3.
// R9: SINGLE-PASS when D == 8*THREADS (our shape): the row lives in
// registers (2 float4/thread) between the norm reduce and the convert,
// halving x reads from HBM (64 -> 32 MB). Two-pass fallback otherwise.
// Also zero-inits d_out (block 0) so the separate memset launch is dropped.
// ---------------------------------------------------------------------------
__launch_bounds__(THREADS)
__global__ void norm_conv_fp8_kernel(const float* __restrict__ x,
                                     unsigned char* __restrict__ xq,
                                     float* __restrict__ out, int D) {
    const int row = blockIdx.x;
    const float4* x4 = (const float4*)(x + (size_t)row * D);
    const int tid = threadIdx.x;
    if (row == 0 && tid == 0) out[0] = 0.f;
    __shared__ float red[THREADS / 64 + 1];

    if (D == THREADS * 8) {
        // ---- single-pass: row stays in registers ----
        float4 v0 = x4[tid * 2];
        float4 v1 = x4[tid * 2 + 1];
        float s = v0.x * v0.x + v0.y * v0.y + v0.z * v0.z + v0.w * v0.w
                + v1.x * v1.x + v1.y * v1.y + v1.z * v1.z + v1.w * v1.w;
#pragma unroll
        for (int off = 32; off > 0; off >>= 1) s += __shfl_down(s, off, 64);
        if ((tid & 63) == 0) red[tid >> 6] = s;
        __syncthreads();
        if (tid == 0) {
            float tot = 0.f;
#pragma unroll
            for (int w = 0; w < THREADS / 64; ++w) tot += red[w];
            red[THREADS / 64] = FP8_SCALE / fmaxf(sqrtf(tot), 1e-12f);
        }
        __syncthreads();
        const float sc = red[THREADS / 64];
        int lo = __builtin_amdgcn_cvt_pk_fp8_f32(v0.x * sc, v0.y * sc, 0, 0);
        lo = __builtin_amdgcn_cvt_pk_fp8_f32(v0.z * sc, v0.w * sc, lo, 1);
        int hi = __builtin_amdgcn_cvt_pk_fp8_f32(v1.x * sc, v1.y * sc, 0, 0);
        hi = __builtin_amdgcn_cvt_pk_fp8_f32(v1.z * sc, v1.w * sc, hi, 1);
        int2 o; o.x = lo; o.y = hi;
        ((int2*)(xq + (size_t)row * D))[tid] = o;
        return;
    }

    // ---- generic two-pass fallback ----
    float s = 0.f;
    for (int b = tid * 2; b * 4 < D; b += THREADS * 2) {
        float4 v0 = x4[b];
        float4 v1 = x4[b + 1];
        s += v0.x * v0.x + v0.y * v0.y + v0.z * v0.z + v0.w * v0.w
           + v1.x * v1.x + v1.y * v1.y + v1.z * v1.z + v1.w * v1.w;
    }
#pragma unroll
    for (int off = 32; off > 0; off >>= 1) s += __shfl_down(s, off, 64);
    if ((tid & 63) == 0) red[tid >> 6] = s;
    __syncthreads();
    if (tid == 0) {
        float tot = 0.f;
#pragma unroll
        for (int w = 0; w < THREADS / 64; ++w) tot += red[w];
        red[THREADS / 64] = FP8_SCALE / fmaxf(sqrtf(tot), 1e-12f);
    }
    __syncthreads();
    const float sc = red[THREADS / 64];

    int2* outq = (int2*)(xq + (size_t)row * D);
    for (int b = tid * 2; b * 4 < D; b += THREADS * 2) {
        float4 v0 = x4[b];
        float4 v1 = x4[b + 1];
        int lo = __builtin_amdgcn_cvt_pk_fp8_f32(v0.x * sc, v0.y * sc, 0, 0);
        lo = __builtin_amdgcn_cvt_pk_fp8_f32(v0.z * sc, v0.w * sc, lo, 1);
        int hi = __builtin_amdgcn_cvt_pk_fp8_f32(v1.x * sc, v1.y * sc, 0, 0);
        hi = __builtin_amdgcn_cvt_pk_fp8_f32(v1.z * sc, v1.w * sc, hi, 1);
        int2 o; o.x = lo; o.y = hi;
        outq[b >> 1] = o;
    }
}

// Plain inv-norm (fallback path).
__global__ void row_inv_norm_kernel(const float* __restrict__ x,
                                    float* __restrict__ inv_norm, int D) {
    const int row = blockIdx.x;
    const float4* x4 = (const float4*)(x + (size_t)row * D);
    const int nf4 = D >> 2;
    float s = 0.f;
    for (int i = threadIdx.x; i < nf4; i += THREADS) {
        float4 v = x4[i];
        s += v.x * v.x + v.y * v.y + v.z * v.z + v.w * v.w;
    }
#pragma unroll
    for (int off = 32; off > 0; off >>= 1) s += __shfl_down(s, off, 64);
    __shared__ float red[THREADS / 64];
    if ((threadIdx.x & 63) == 0) red[threadIdx.x >> 6] = s;
    __syncthreads();
    if (threadIdx.x == 0) {
        float tot = 0.f;
#pragma unroll
        for (int w = 0; w < THREADS / 64; ++w) tot += red[w];
        inv_norm[row] = 1.0f / fmaxf(sqrtf(tot), 1e-12f);
    }
}

#define GLDS16(g, l)                                                          \
    __builtin_amdgcn_global_load_lds(                                         \
        (const __attribute__((address_space(1))) unsigned int*)(g),           \
        (__attribute__((address_space(3))) unsigned int*)(l), 16, 0, 0)

// ---------------------------------------------------------------------------
// Kernel B: SYMMETRIC fp8 Gram. R9 = R8 + s_setprio around the MFMA cluster.
// R8 status: spill ELIMINATED (WRITE_SIZE 4224 KB exact, VGPR 68) via the
// pass-2 CSE fence; gram 77.2 us. All pipes <35% -> latency-bound.
// setprio rationale (T5): each CU hosts 2-3 mutually-unsynchronized blocks
// (barriers are per-block) -> wave phase diversity exists -> elevating MFMA
// waves lets the CU scheduler prefer them over other blocks' staging waves.
// (m190's null was single-block lockstep; m191 attn +4-7% with independent
// blocks.) Bank conflicts (4.4M) are the INHERENT 4-way of wave64
// ds_read_b64 (128 bank-slots / 32 banks) - not fixable, not chased.
// Config: __launch_bounds__(256,3), 3 blocks/CU, single round; triple-
// buffered staging (3 x 16 KB LDS), counted vmcnt: per iter
// s_waitcnt vmcnt(4) -> s_barrier -> stage t+2 -> ds_read + 32 MFMA.
// Staging swizzle (QBK=64): LDS slot q of row r holds global chunk
// q ^ ((r>>1)&3); fragment read of k-slot sl=ks*4+quad lives at byte
// r*64 + (((sl>>1)^((r>>1)&3))<<4) + ((sl&1)<<3); ks=1 is ks=0 ^ 32.
// vals: 0 s_pos_intra 1 cnt_pi 2 s_pos_cross 3 cnt_pc
//       4 DE_neg_intra 5 E_neg_intra 6 DE_neg_cross 7 E_neg_cross
// ---------------------------------------------------------------------------
__launch_bounds__(THREADS, 3)
__global__ void gram_fp8_kernel(const unsigned char* __restrict__ xq,
                                const int* __restrict__ targets,
                                const int* __restrict__ sub,
                                float* __restrict__ pr,
                                float* __restrict__ pc,
                                int D) {
    __shared__ unsigned char As[3][BM * QBK];   // 3 x 8 KB
    __shared__ unsigned char Bs[3][BM * QBK];   // 3 x 8 KB

    // XCD-chunked tile mapping (bijective: gridDim.x % 8 == 0).
    int tk = blockIdx.x;
    if ((gridDim.x & 7) == 0) {
        const int per = gridDim.x >> 3;
        tk = (tk & 7) * per + (tk >> 3);
    }

    // Triangular decode: tk = bx*(bx+1)/2 + by, by <= bx.
    int bx = (int)((sqrtf(8.0f * tk + 1.0f) - 1.0f) * 0.5f);
    while ((bx + 1) * (bx + 2) / 2 <= tk) ++bx;
    while (bx * (bx + 1) / 2 > tk) --bx;
    const int by = tk - bx * (bx + 1) / 2;

    const int tid = threadIdx.x;
    const int w = tid >> 6;          // wave 0..3
    const int lane = tid & 63;
    const int wm = w >> 1;           // row half (0..1)
    const int wn = w & 1;            // col half (0..1)
    const int quad = lane >> 4;
    const int cl = lane & 15;

    const int rowA0 = by * BM;
    const int colB0 = bx * BM;

    // Staging: per matrix 512 chunks of 16B (128 rows x 4); thread covers
    // chunks c = l*256 + tid, l=0..1. r = c>>2 = l*64 + (tid>>2);
    // source slot qs = (tid&3) ^ ((r>>1)&3) = (tid&3) ^ ((tid>>3)&3).
    const int qs = (tid & 3) ^ ((tid >> 3) & 3);
    const unsigned char* sA[2];
    const unsigned char* sB[2];
    int dof[2];
#pragma unroll
    for (int l = 0; l < 2; ++l) {
        const int r = l * 64 + (tid >> 2);
        sA[l] = xq + (size_t)(rowA0 + r) * D + qs * 16;
        sB[l] = xq + (size_t)(colB0 + r) * D + qs * 16;
        dof[l] = (l * 256 + w * 64) * 16;   // wave-uniform byte base
    }

    // Fragment byte offsets for ks=0; ks=1 = ^32 (chunk bit1 flips).
    int aoff[4], boff[4];
#pragma unroll
    for (int mi = 0; mi < 4; ++mi) {
        const int ar = wm * 64 + mi * 16 + cl;
        aoff[mi] = ar * QBK + (((quad >> 1) ^ ((ar >> 1) & 3)) << 4)
                 + ((quad & 1) << 3);
    }
#pragma unroll
    for (int ni = 0; ni < 4; ++ni) {
        const int br = wn * 64 + ni * 16 + cl;
        boff[ni] = br * QBK + (((quad >> 1) ^ ((br >> 1) & 3)) << 4)
                 + ((quad & 1) << 3);
    }

    f32x4 accv[4][4];
#pragma unroll
    for (int mi = 0; mi < 4; ++mi)
#pragma unroll
        for (int ni = 0; ni < 4; ++ni) accv[mi][ni] = (f32x4)(0.f);

    const int nIter = D / QBK;

    // Prologue: stage tiles 0,1 into bufs 0,1 (8 vmem/wave outstanding).
#pragma unroll
    for (int l = 0; l < 2; ++l) {
        GLDS16(sA[l], &As[0][0] + dof[l]);
        GLDS16(sB[l], &Bs[0][0] + dof[l]);
    }
#pragma unroll
    for (int l = 0; l < 2; ++l) {
        GLDS16(sA[l] + QBK, &As[1][0] + dof[l]);
        GLDS16(sB[l] + QBK, &Bs[1][0] + dof[l]);
    }

    int cs = 0;          // t % 3
    int ps = 2;          // (t+2) % 3
    for (int t = 0; t < nIter; ++t) {
        // Tile t's 4 loads done; tile t+1's 4 may remain in flight.
        if (t + 1 < nIter)
            asm volatile("s_waitcnt vmcnt(4)" ::: "memory");
        else
            asm volatile("s_waitcnt vmcnt(0)" ::: "memory");
        __builtin_amdgcn_s_barrier();

        if (t + 2 < nIter) {
            const int kb = (t + 2) * QBK;
#pragma unroll
            for (int l = 0; l < 2; ++l) {
                GLDS16(sA[l] + kb, &As[ps][0] + dof[l]);
                GLDS16(sB[l] + kb, &Bs[ps][0] + dof[l]);
            }
        }

        const unsigned char* Ac = &As[cs][0];
        const unsigned char* Bc = &Bs[cs][0];
        long af[4], bf[4];
#pragma unroll
        for (int mi = 0; mi < 4; ++mi)
            af[mi] = *(const long*)(Ac + aoff[mi]);
#pragma unroll
        for (int ni = 0; ni < 4; ++ni)
            bf[ni] = *(const long*)(Bc + boff[ni]);
        __builtin_amdgcn_s_setprio(1);
#pragma unroll
        for (int mi = 0; mi < 4; ++mi)
#pragma unroll
            for (int ni = 0; ni < 4; ++ni)
                accv[mi][ni] = __builtin_amdgcn_mfma_f32_16x16x32_fp8_fp8(
                    af[mi], bf[ni], accv[mi][ni], 0, 0, 0);
#pragma unroll
        for (int mi = 0; mi < 4; ++mi)
            af[mi] = *(const long*)(Ac + (aoff[mi] ^ 32));
#pragma unroll
        for (int ni = 0; ni < 4; ++ni)
            bf[ni] = *(const long*)(Bc + (boff[ni] ^ 32));
#pragma unroll
        for (int mi = 0; mi < 4; ++mi)
#pragma unroll
            for (int ni = 0; ni < 4; ++ni)
                accv[mi][ni] = __builtin_amdgcn_mfma_f32_16x16x32_fp8_fp8(
                    af[mi], bf[ni], accv[mi][ni], 0, 0, 0);
        __builtin_amdgcn_s_setprio(0);

        cs = (cs == 2) ? 0 : cs + 1;
        ps = (ps == 2) ? 0 : ps + 1;
    }

    // ---------------- epilogue pass 1: row partials ----------------
    // C/D map: col = cl, row = quad*4 + reg. Dots carry scale 65536.
    // accv is READ-ONLY from here on (stays in ACC regs; no write-back).
    int tj[4], sj[4];
#pragma unroll
    for (int ni = 0; ni < 4; ++ni) {
        const int gc = colB0 + wn * 64 + ni * 16 + cl;
        tj[ni] = targets[gc];
        sj[ni] = sub[gc];
    }

    float* rowp = (float*)&As[0][0];   // reuse buf0: [2][128][8] = 8 KB
#pragma unroll
    for (int mi = 0; mi < 4; ++mi) {
#pragma unroll
        for (int r = 0; r < 4; ++r) {
            const int rloc = wm * 64 + mi * 16 + quad * 4 + r;
            const int gi = rowA0 + rloc;
            const int ti = targets[gi];     // L1-hot broadcast
            const int si = sub[gi];

            float s0 = 0.f, s1 = 0.f, s2 = 0.f, s3 = 0.f;
            float s4 = 0.f, s5 = 0.f, s6 = 0.f, s7 = 0.f;
#pragma unroll
            for (int ni = 0; ni < 4; ++ni) {
                const int gj = colB0 + wn * 64 + ni * 16 + cl;
                const float d2 =
                    fmaf(-2.0f * INV_SCALE2, accv[mi][ni][r], 2.0f);
                const float dd = sqrtf(fmaxf(d2, 1e-12f));
                const bool same = (ti == tj[ni]);
                const bool intra = (si == sj[ni]);
                const bool pos = same && (gi != gj);
                const bool neg = !same;
                const float mg = intra ? 1.4f : 0.7f;
                const float v = fmaxf(dd - mg, 0.f);
                const float e = __expf(-dd);   // e^alpha folded in finalize
                const float de = dd * e;
                if (pos && intra)  { s0 += v;  s1 += 1.f; }
                if (pos && !intra) { s2 += v;  s3 += 1.f; }
                if (neg && intra)  { s4 += de; s5 += e; }
                if (neg && !intra) { s6 += de; s7 += e; }
            }
#pragma unroll
            for (int off = 1; off < 16; off <<= 1) {
                s0 += __shfl_xor(s0, off, 64);
                s1 += __shfl_xor(s1, off, 64);
                s2 += __shfl_xor(s2, off, 64);
                s3 += __shfl_xor(s3, off, 64);
                s4 += __shfl_xor(s4, off, 64);
                s5 += __shfl_xor(s5, off, 64);
                s6 += __shfl_xor(s6, off, 64);
                s7 += __shfl_xor(s7, off, 64);
            }
            if (cl == 0) {
                float* dst = rowp + ((wn << 7) + rloc) * 8;
                float4 p0 = {s0, s1, s2, s3};
                float4 p1 = {s4, s5, s6, s7};
                *(float4*)(dst) = p0;
                *(float4*)(dst + 4) = p1;
            }
        }
    }
    __syncthreads();
    {
        const size_t prbase = (size_t)tk * 1024;
        for (int i = tid; i < 1024; i += THREADS)
            pr[prbase + i] = rowp[i] + rowp[1024 + i];
    }

    // ------- epilogue pass 2: col partials (dd recomputed for real) -------
    // The asm "+v" makes the accv read opaque: defeats cross-pass CSE that
    // otherwise keeps 64 dd/e/de values live from pass 1 (R5==R7 evidence;
    // R8 confirmed: WRITE_SIZE 40656 -> 4224 KB, gram 86.5 -> 77.2 us).
    float* colp = (float*)&Bs[0][0];   // reuse buf0: [2][128][8] = 8 KB
#pragma unroll
    for (int ni = 0; ni < 4; ++ni) {
        const int gj = colB0 + wn * 64 + ni * 16 + cl;
        const int tjc = tj[ni];
        const int sjc = sj[ni];
        float s0 = 0.f, s1 = 0.f, s2 = 0.f, s3 = 0.f;
        float s4 = 0.f, s5 = 0.f, s6 = 0.f, s7 = 0.f;
#pragma unroll
        for (int mi = 0; mi < 4; ++mi) {
#pragma unroll
            for (int r = 0; r < 4; ++r) {
                const int gi = rowA0 + wm * 64 + mi * 16 + quad * 4 + r;
                const int ti = targets[gi];     // L1-hot reload
                const int si = sub[gi];
                float dot = accv[mi][ni][r];
                asm volatile("" : "+v"(dot));   // CSE fence (see header)
                const float d2 = fmaf(-2.0f * INV_SCALE2, dot, 2.0f);
                const float dd = sqrtf(fmaxf(d2, 1e-12f));
                const bool same = (ti == tjc);
                const bool intra = (si == sjc);
                const bool pos = same && (gi != gj);
                const bool neg = !same;
                const float mg = intra ? 1.4f : 0.7f;
                const float v = fmaxf(dd - mg, 0.f);
                const float e = __expf(-dd);
                const float de = dd * e;
                if (pos && intra)  { s0 += v;  s1 += 1.f; }
                if (pos && !intra) { s2 += v;  s3 += 1.f; }
                if (neg && intra)  { s4 += de; s5 += e; }
                if (neg && !intra) { s6 += de; s7 += e; }
            }
        }
        s0 += __shfl_xor(s0, 16, 64); s0 += __shfl_xor(s0, 32, 64);
        s1 += __shfl_xor(s1, 16, 64); s1 += __shfl_xor(s1, 32, 64);
        s2 += __shfl_xor(s2, 16, 64); s2 += __shfl_xor(s2, 32, 64);
        s3 += __shfl_xor(s3, 16, 64); s3 += __shfl_xor(s3, 32, 64);
        s4 += __shfl_xor(s4, 16, 64); s4 += __shfl_xor(s4, 32, 64);
        s5 += __shfl_xor(s5, 16, 64); s5 += __shfl_xor(s5, 32, 64);
        s6 += __shfl_xor(s6, 16, 64); s6 += __shfl_xor(s6, 32, 64);
        s7 += __shfl_xor(s7, 16, 64); s7 += __shfl_xor(s7, 32, 64);
        if (lane < 16) {
            const int colloc = wn * 64 + ni * 16 + lane;
            float* dst = colp + ((wm << 7) + colloc) * 8;
            float4 p0 = {s0, s1, s2, s3};
            float4 p1 = {s4, s5, s6, s7};
            *(float4*)(dst) = p0;
            *(float4*)(dst + 4) = p1;
        }
    }
    __syncthreads();
    {
        const float om = (bx == by) ? 0.f : 1.f;   // diag: zero col side
        const size_t pcbase = (size_t)tk * 1024;
        for (int i = tid; i < 1024; i += THREADS)
            pc[pcbase + i] = (colp[i] + colp[1024 + i]) * om;
    }
}

// ---------------------------------------------------------------------------
// Kernel C: gather 33 slices per row (nbx-B from pr, B+1 from pc; the
// diagonal pc slice is pre-zeroed), combine ratios, global mean.
// ---------------------------------------------------------------------------
__global__ void finalize_sym_kernel(const float* __restrict__ pr,
                                    const float* __restrict__ pc,
                                    float* __restrict__ out, int N, int nbx) {
    const int tid = threadIdx.x;
    const int rloc16 = tid >> 4;
    const int st = tid & 15;
    const int i = blockIdx.x * 16 + rloc16;
    const int B = i >> 7;
    const int rl = i & 127;
    const int nrow = nbx - B;          // pr-slice count
    const int ntot = nbx + 1;          // total slices (one is zero)

    float a0 = 0.f, a1 = 0.f, a2 = 0.f, a3 = 0.f;
    float a4 = 0.f, a5 = 0.f, a6 = 0.f, a7 = 0.f;
    for (int s = st; s < ntot; s += 16) {
        const float* base;
        if (s < nrow) {
            const int bxx = B + s;
            base = pr + ((size_t)(bxx * (bxx + 1) / 2 + B) * 128 + rl) * 8;
        } else {
            const int byy = s - nrow;
            base = pc + ((size_t)(B * (B + 1) / 2 + byy) * 128 + rl) * 8;
        }
        float4 u0 = *(const float4*)(base);
        float4 u1 = *(const float4*)(base + 4);
        a0 += u0.x; a1 += u0.y; a2 += u0.z; a3 += u0.w;
        a4 += u1.x; a5 += u1.y; a6 += u1.z; a7 += u1.w;
    }
#pragma unroll
    for (int off = 1; off < 16; off <<= 1) {
        a0 += __shfl_xor(a0, off, 64);
        a1 += __shfl_xor(a1, off, 64);
        a2 += __shfl_xor(a2, off, 64);
        a3 += __shfl_xor(a3, off, 64);
        a4 += __shfl_xor(a4, off, 64);
        a5 += __shfl_xor(a5, off, 64);
        a6 += __shfl_xor(a6, off, 64);
        a7 += __shfl_xor(a7, off, 64);
    }
    __shared__ float lred[16];
    if (st == 0) {
        const float l = a0 / (a1 + EPSV) + a2 / (a3 + EPSV)
            + (C1E * fmaf(2.4f, a5, -a4)) / (C1E * a5 + EPSV)
            + (C2E * fmaf(2.2f, a7, -a6)) / (C2E * a7 + EPSV);
        lred[rloc16] = l;
    }
    __syncthreads();
    if (tid == 0) {
        float tot = 0.f;
#pragma unroll
        for (int k2 = 0; k2 < 16; ++k2) tot += lred[k2];
        atomicAdd(out, tot / (float)N);
    }
}

// ---------------------------------------------------------------------------
// Fallback path (144 KB ws): fp32 tile GEMM + atomic epilogue (R1, known-good)
// ---------------------------------------------------------------------------
__launch_bounds__(THREADS, 2)
__global__ void dist_loss_kernel(const float* __restrict__ x,
                                 const int* __restrict__ targets,
                                 const int* __restrict__ sub,
                                 const float* __restrict__ inv_norm,
                                 float* __restrict__ acc,
                                 int N, int D) {
    __shared__ float Asf[16][128];
    __shared__ float Bsf[16][128];

    const int nbx = N / 128;
    const int bx = blockIdx.x % nbx;
    const int by = blockIdx.x / nbx;
    const int tid = threadIdx.x;
    const int tx = tid & 15;
    const int ty = tid >> 4;
    const int rowA0 = by * 128;
    const int colB0 = bx * 128;
    const float* Abase = x + (size_t)rowA0 * D;
    const float* Bbase = x + (size_t)colB0 * D;

    float accv[8][8];
#pragma unroll
    for (int r = 0; r < 8; ++r)
#pragma unroll
        for (int c = 0; c < 8; ++c) accv[r][c] = 0.f;

    for (int kb = 0; kb < D; kb += 16) {
#pragma unroll
        for (int l = 0; l < 2; ++l) {
            const int f = tid + l * THREADS;
            const int row = f >> 2;
            const int kq = (f & 3) << 2;
            float4 va = *(const float4*)(Abase + (size_t)row * D + kb + kq);
            float4 vb = *(const float4*)(Bbase + (size_t)row * D + kb + kq);
            Asf[kq + 0][row] = va.x; Asf[kq + 1][row] = va.y;
            Asf[kq + 2][row] = va.z; Asf[kq + 3][row] = va.w;
            Bsf[kq + 0][row] = vb.x; Bsf[kq + 1][row] = vb.y;
            Bsf[kq + 2][row] = vb.z; Bsf[kq + 3][row] = vb.w;
        }
        __syncthreads();
#pragma unroll
        for (int k = 0; k < 16; ++k) {
            float4 a0 = *(const float4*)&Asf[k][ty * 8];
            float4 a1 = *(const float4*)&Asf[k][ty * 8 + 4];
            float4 b0 = *(const float4*)&Bsf[k][tx * 8];
            float4 b1 = *(const float4*)&Bsf[k][tx * 8 + 4];
            float ar[8] = {a0.x, a0.y, a0.z, a0.w, a1.x, a1.y, a1.z, a1.w};
            float br[8] = {b0.x, b0.y, b0.z, b0.w, b1.x, b1.y, b1.z, b1.w};
#pragma unroll
            for (int r = 0; r < 8; ++r)
#pragma unroll
                for (int c = 0; c < 8; ++c)
                    accv[r][c] = fmaf(ar[r], br[c], accv[r][c]);
        }
        __syncthreads();
    }

    const int row_base = rowA0 + ty * 8;
    const int col_base = colB0 + tx * 8;
    int tjc[8], sjc[8];
    float invj[8];
#pragma unroll
    for (int c = 0; c < 8; ++c) {
        tjc[c] = targets[col_base + c];
        sjc[c] = sub[col_base + c];
        invj[c] = inv_norm[col_base + c];
    }
#pragma unroll
    for (int r = 0; r < 8; ++r) {
        const int gi = row_base + r;
        const int ti = targets[gi];
        const int si = sub[gi];
        const float invi = inv_norm[gi];
        float s0 = 0.f, s1 = 0.f, s2 = 0.f, s3 = 0.f;
        float s4 = 0.f, s5 = 0.f, s6 = 0.f, s7 = 0.f;
#pragma unroll
        for (int c = 0; c < 8; ++c) {
            const int gj = col_base + c;
            const float dot = accv[r][c] * invi * invj[c];
            const float dd = sqrtf(fmaxf(2.f - 2.f * dot, 1e-12f));
            const bool same = (ti == tjc[c]);
            const bool intra = (si == sjc[c]);
            const bool pos = same && (gi != gj);
            const bool neg = !same;
            const float df = (intra ? 2.4f : 2.2f) - dd;
            const float wgt = __expf(df);
            const float v = fmaxf(dd - (intra ? 1.4f : 0.7f), 0.f);
            if (pos && intra)  { s0 += v; s1 += 1.f; }
            if (pos && !intra) { s2 += v; s3 += 1.f; }
            if (neg && intra)  { s4 += df * wgt; s5 += wgt; }
            if (neg && !intra) { s6 += df * wgt; s7 += wgt; }
        }
#pragma unroll
        for (int off = 1; off < 16; off <<= 1) {
            s0 += __shfl_xor(s0, off, 64);
            s1 += __shfl_xor(s1, off, 64);
            s2 += __shfl_xor(s2, off, 64);
            s3 += __shfl_xor(s3, off, 64);
            s4 += __shfl_xor(s4, off, 64);
            s5 += __shfl_xor(s5, off, 64);
            s6 += __shfl_xor(s6, off, 64);
            s7 += __shfl_xor(s7, off, 64);
        }
        if (tx == 0) {
            float* a = acc + (size_t)gi * 8;
            atomicAdd(a + 0, s0); atomicAdd(a + 1, s1);
            atomicAdd(a + 2, s2); atomicAdd(a + 3, s3);
            atomicAdd(a + 4, s4); atomicAdd(a + 5, s5);
            atomicAdd(a + 6, s6); atomicAdd(a + 7, s7);
        }
    }
}

__global__ void finalize_kernel(const float* __restrict__ acc,
                                float* __restrict__ out, int N) {
    float s = 0.f;
    for (int i = threadIdx.x; i < N; i += THREADS) {
        const float* a = acc + (size_t)i * 8;
        s += a[0] / (a[1] + EPSV) + a[2] / (a[3] + EPSV)
           + a[4] / (a[5] + EPSV) + a[6] / (a[7] + EPSV);
    }
#pragma unroll
    for (int off = 32; off > 0; off >>= 1) s += __shfl_down(s, off, 64);
    __shared__ float red[THREADS / 64];
    if ((threadIdx.x & 63) == 0) red[threadIdx.x >> 6] = s;
    __syncthreads();
    if (threadIdx.x == 0) {
        float tot = 0.f;
#pragma unroll
        for (int w = 0; w < THREADS / 64; ++w) tot += red[w];
        out[0] = tot / (float)N;
    }
}

// ---------------------------------------------------------------------------
extern "C" void kernel_launch(void* const* d_in, const int* in_sizes, int n_in,
                              void* d_out, int out_size, void* d_ws, size_t ws_size,
                              hipStream_t stream) {
    const float* x = (const float*)d_in[0];
    const int* targets = (const int*)d_in[1];
    const int* sub = (const int*)d_in[2];
    const int N = in_sizes[1];
    const int D = in_sizes[0] / N;

    const int nbx = N / BM;
    const int T = nbx * (nbx + 1) / 2;
    const size_t sliceB = (size_t)T * 128 * 8 * sizeof(float);
    const size_t need = (size_t)N * D + 2 * sliceB;   // fp8: N*D bytes

    if (ws_size >= need) {
        unsigned char* xq = (unsigned char*)d_ws;     // N*D fp8
        float* pr = (float*)((char*)d_ws + (size_t)N * D);
        float* pc = pr + (size_t)T * 128 * 8;

        norm_conv_fp8_kernel<<<N, THREADS, 0, stream>>>(x, xq,
                                                        (float*)d_out, D);
        gram_fp8_kernel<<<T, THREADS, 0, stream>>>(xq, targets, sub,
                                                   pr, pc, D);
        finalize_sym_kernel<<<N / 16, THREADS, 0, stream>>>(
            pr, pc, (float*)d_out, N, nbx);
    } else {
        // Fallback (144 KB ws): fp32 path, known-good from round 1.
        float* inv_norm = (float*)d_ws;
        float* acc = inv_norm + N;
        hipMemsetAsync(acc, 0, (size_t)N * 8 * sizeof(float), stream);
        row_inv_norm_kernel<<<N, THREADS, 0, stream>>>(x, inv_norm, D);
        dist_loss_kernel<<<nbx * nbx, THREADS, 0, stream>>>(
            x, targets, sub, inv_norm, acc, N, D);
        finalize_kernel<<<1, THREADS, 0, stream>>>(acc, (float*)d_out, N);
    }
}